// Round 6
// baseline (445.803 us; speedup 1.0000x reference)
//
#include <hip/hip_runtime.h>
#include <hip/hip_bf16.h>
#include <math.h>

#define B_ 16
#define C_ 512
#define N_ 4096
#define NCOL (B_ * N_)  // 65536 columns (b, hw)

typedef short bf16x8 __attribute__((ext_vector_type(8)));
typedef ushort ushort8_t __attribute__((ext_vector_type(8)));
typedef float f32x4 __attribute__((ext_vector_type(4)));

__device__ __forceinline__ ushort f2bf(float f) {
    unsigned u = __float_as_uint(f);
    unsigned r = (u + 0x7FFFu + ((u >> 16) & 1u)) >> 16;
    return (ushort)r;
}
__device__ __forceinline__ float bf2f(ushort u) {
    return __uint_as_float((unsigned)u << 16);
}
__device__ __forceinline__ void gload_lds16(const void* g, void* l) {
    __builtin_amdgcn_global_load_lds(
        (const __attribute__((address_space(1))) unsigned int*)g,
        (__attribute__((address_space(3))) unsigned int*)l, 16, 0, 0);
}

// ---------------------------------------------------------------------------
// weight prep: Wb[i] = bf16(W[i] * g[c])  (g optional, c = flat%512)
// ---------------------------------------------------------------------------
__global__ __launch_bounds__(256) void wprep_k(const float* __restrict__ W,
                                               const float* __restrict__ g,
                                               ushort* __restrict__ Wb, int nvec)
{
    int i = blockIdx.x * 256 + threadIdx.x;
    if (i >= nvec) return;
    float4 wv = reinterpret_cast<const float4*>(W)[i];
    if (g) {
        const float4 gv = *reinterpret_cast<const float4*>(g + ((i * 4) & 511));
        wv.x *= gv.x; wv.y *= gv.y; wv.z *= gv.z; wv.w *= gv.w;
    }
    ushort4 u;
    u.x = f2bf(wv.x); u.y = f2bf(wv.y); u.z = f2bf(wv.z); u.w = f2bf(wv.w);
    reinterpret_cast<ushort4*>(Wb)[i] = u;
}

// ---------------------------------------------------------------------------
// transpose+convert+colnorm-partial:
//   Xt[b][n][c] = bf16(x[b][c][n]);  csq1[ctile][b*4096+n] += sum_c x^2
// ---------------------------------------------------------------------------
__global__ __launch_bounds__(256) void transpose_k(const float* __restrict__ X,
                                                   ushort* __restrict__ Xt,
                                                   float* __restrict__ csq1)
{
    __shared__ float t[64][65];
    __shared__ float sq[4][64];
    const int b = blockIdx.z, n0 = blockIdx.x * 64, c0 = blockIdx.y * 64;
    const int tid = threadIdx.x;
    const int tx = tid & 63, ty = tid >> 6;
    const float* xp = X + ((size_t)b * C_ + c0) * N_ + n0;
    float local = 0.f;
    #pragma unroll
    for (int i = 0; i < 16; ++i) {
        float v = xp[(size_t)(ty + 4 * i) * N_ + tx];
        t[ty + 4 * i][tx] = v;
        local += v * v;
    }
    sq[ty][tx] = local;
    __syncthreads();
    #pragma unroll
    for (int i = 0; i < 4; ++i) {
        int nl = (tid >> 4) + i * 16;
        int cl = (tid & 15) * 4;
        ushort4 u;
        u.x = f2bf(t[cl + 0][nl]);
        u.y = f2bf(t[cl + 1][nl]);
        u.z = f2bf(t[cl + 2][nl]);
        u.w = f2bf(t[cl + 3][nl]);
        *reinterpret_cast<ushort4*>(Xt + ((size_t)b * N_ + n0 + nl) * 512 + c0 + cl) = u;
    }
    if (tid < 64)
        csq1[(size_t)blockIdx.y * NCOL + (size_t)b * N_ + n0 + tid] =
            sq[0][tid] + sq[1][tid] + sq[2][tid] + sq[3][tid];
}

// ---------------------------------------------------------------------------
// reduce 8 csq1 partials -> rs1 = sqrt(512)/max(||x_col||, eps)
// ---------------------------------------------------------------------------
__global__ __launch_bounds__(256) void rs1_reduce_k(const float* __restrict__ csq1,
                                                    float* __restrict__ rs1)
{
    int col = blockIdx.x * 256 + threadIdx.x;
    float s = 0.f;
    #pragma unroll
    for (int j = 0; j < 8; ++j) s += csq1[(size_t)j * NCOL + col];
    rs1[col] = 22.627416998f / fmaxf(sqrtf(s), 1e-12f);
}

// ---------------------------------------------------------------------------
// MFMA GEMM1 (256x256 tile, 8 waves 2x4, BK=64, double-buffered LDS,
// per-phase interleave + counted vmcnt):  acc[o][n] = sum_c A[o][c]*Bt[b][n][c]
// Per K-tile: 4 phases (kk x m-half), each {ds_read subtile || stage 2 gloads
// of next tile} -> barrier -> lgkmcnt(0) -> setprio-wrapped 16 MFMA -> barrier.
// vmcnt(2) only at phase 0 (counted; the 2 newest loads are next-tile's).
// Epilogue: acc *= rs1[b][n];
//   part 0 (q): softmax over d (in-wave reduce) * 0.125 -> q bf16
//   part 1/2 (k/v): -> bf16 raw
// ---------------------------------------------------------------------------
__global__ __launch_bounds__(512, 2)
void mfma_gemm(const ushort* __restrict__ A, const ushort* __restrict__ Bt,
               const float* __restrict__ rs1,
               ushort* __restrict__ qd, ushort* __restrict__ kd,
               ushort* __restrict__ vd)
{
    // lds[buf][A/B][256 rows][8 chunks][16B]
    __shared__ __align__(16) char lds[2][2][32768];
    const int b  = blockIdx.z;
    const int n0 = blockIdx.x * 256;
    const int m0 = blockIdx.y * 256;
    const int tid = threadIdx.x;
    const int w = tid >> 6, l = tid & 63;
    const int wm = w >> 2, wn = w & 3;          // 2 x 4 waves
    const int lq = l >> 4, lr = l & 15;
    const ushort* Bb = Bt + (size_t)b * N_ * 512;

    f32x4 acc[8][4];
    #pragma unroll
    for (int i = 0; i < 8; ++i)
        #pragma unroll
        for (int j = 0; j < 4; ++j)
            #pragma unroll
            for (int r = 0; r < 4; ++r) acc[i][j][r] = 0.f;

    // stage step i (0..3) of tile t: 2 gloads/thread (A and B), source chunk
    // pre-swizzled (ch ^= row&7), LDS dest linear.
#define STAGE_STEP(t, i)                                                      \
    do {                                                                      \
        const int kb_ = (t) * 128;                                            \
        const int idx_ = (i) * 512 + tid;                                     \
        const int r_ = idx_ >> 3;                                             \
        const int ch_ = (idx_ & 7) ^ (r_ & 7);                                \
        gload_lds16((const char*)A + (size_t)(m0 + r_) * 1024 + kb_ + ch_ * 16,\
                    &lds[(t) & 1][0][idx_ * 16]);                             \
        gload_lds16((const char*)Bb + (size_t)(n0 + r_) * 1024 + kb_ + ch_ * 16,\
                    &lds[(t) & 1][1][idx_ * 16]);                             \
    } while (0)

    #pragma unroll
    for (int i = 0; i < 4; ++i) STAGE_STEP(0, i);

    bf16x8 bfr[4];
    #pragma unroll 2
    for (int t = 0; t < 8; ++t) {
        const char* As = lds[t & 1][0];
        const char* Bs = lds[t & 1][1];
        #pragma unroll
        for (int ph = 0; ph < 4; ++ph) {
            const int kk = ph >> 1, mg = ph & 1;
            bf16x8 af[4];
            if (ph != 0) {
                // pre-barrier ds_read: tile-t data is stable since phase 0
                #pragma unroll
                for (int m2 = 0; m2 < 4; ++m2) {
                    int ra = wm * 128 + (mg * 4 + m2) * 16 + lr;
                    int ch = (kk * 4 + lq) ^ (ra & 7);
                    af[m2] = *(const bf16x8*)(As + ra * 128 + ch * 16);
                }
                if (mg == 0) {
                    #pragma unroll
                    for (int nf = 0; nf < 4; ++nf) {
                        int rb = wn * 64 + nf * 16 + lr;
                        int ch = (kk * 4 + lq) ^ (rb & 7);
                        bfr[nf] = *(const bf16x8*)(Bs + rb * 128 + ch * 16);
                    }
                }
            }
            if (t < 7) STAGE_STEP(t + 1, ph);
            if (ph == 0) {
                if (t < 7) { asm volatile("s_waitcnt vmcnt(2)" ::: "memory"); }
                else       { asm volatile("s_waitcnt vmcnt(0)" ::: "memory"); }
            }
            __builtin_amdgcn_s_barrier();
            if (ph == 0) {
                // first phase of the tile: reads must follow the barrier
                #pragma unroll
                for (int m2 = 0; m2 < 4; ++m2) {
                    int ra = wm * 128 + m2 * 16 + lr;
                    int ch = lq ^ (ra & 7);
                    af[m2] = *(const bf16x8*)(As + ra * 128 + ch * 16);
                }
                #pragma unroll
                for (int nf = 0; nf < 4; ++nf) {
                    int rb = wn * 64 + nf * 16 + lr;
                    int ch = lq ^ (rb & 7);
                    bfr[nf] = *(const bf16x8*)(Bs + rb * 128 + ch * 16);
                }
            }
            asm volatile("s_waitcnt lgkmcnt(0)" ::: "memory");
            __builtin_amdgcn_sched_barrier(0);
            __builtin_amdgcn_s_setprio(1);
            #pragma unroll
            for (int m2 = 0; m2 < 4; ++m2)
                #pragma unroll
                for (int nf = 0; nf < 4; ++nf)
                    acc[mg * 4 + m2][nf] = __builtin_amdgcn_mfma_f32_16x16x32_bf16(
                        af[m2], bfr[nf], acc[mg * 4 + m2][nf], 0, 0, 0);
            __builtin_amdgcn_s_setprio(0);
            __builtin_amdgcn_s_barrier();
        }
    }
#undef STAGE_STEP

    const int part = m0 >> 9;                       // block-uniform (0/1/2)
    const int mloc = (m0 & 511) + wm * 128;         // 0/128/256/384 within part
    const int nbase = n0 + wn * 64;
    if (part == 0) {
        // q: *rs1, softmax over the 64 d-rows of each head, *0.125, bf16.
        // wave holds 2 heads: hg=0 -> mf 0..3, hg=1 -> mf 4..7.
        #pragma unroll
        for (int hg = 0; hg < 2; ++hg) {
            const int head = (mloc >> 6) + hg;
            const size_t qrow = ((size_t)b * 8 + head) * 64;
            #pragma unroll
            for (int nf = 0; nf < 4; ++nf) {
                const int n = nbase + nf * 16 + lr;
                const float sc = rs1[(size_t)b * N_ + n];
                float v[4][4];
                float mx = -1e30f;
                #pragma unroll
                for (int m2 = 0; m2 < 4; ++m2)
                    #pragma unroll
                    for (int r = 0; r < 4; ++r) {
                        v[m2][r] = acc[hg * 4 + m2][nf][r] * sc;
                        mx = fmaxf(mx, v[m2][r]);
                    }
                mx = fmaxf(mx, __shfl_xor(mx, 16));
                mx = fmaxf(mx, __shfl_xor(mx, 32));
                float s = 0.f;
                #pragma unroll
                for (int m2 = 0; m2 < 4; ++m2)
                    #pragma unroll
                    for (int r = 0; r < 4; ++r) {
                        v[m2][r] = __expf(v[m2][r] - mx);
                        s += v[m2][r];
                    }
                s += __shfl_xor(s, 16);
                s += __shfl_xor(s, 32);
                const float r8 = 0.125f / s;
                #pragma unroll
                for (int m2 = 0; m2 < 4; ++m2)
                    #pragma unroll
                    for (int r = 0; r < 4; ++r)
                        qd[(qrow + m2 * 16 + lq * 4 + r) * N_ + n] =
                            f2bf(v[m2][r] * r8);
            }
        }
    } else {
        ushort* dst = (part == 1) ? kd : vd;
        #pragma unroll
        for (int nf = 0; nf < 4; ++nf) {
            const int n = nbase + nf * 16 + lr;
            const float sc = rs1[(size_t)b * N_ + n];
            #pragma unroll
            for (int mf = 0; mf < 8; ++mf) {
                const int o = mloc + mf * 16 + lq * 4;
                #pragma unroll
                for (int r = 0; r < 4; ++r)
                    dst[((size_t)b * 512 + o + r) * N_ + n] =
                        f2bf(acc[mf][nf][r] * sc);
            }
        }
    }
}

// ---------------------------------------------------------------------------
// GEMM2 fused: out[b][o][n] = rmsnorm(Wout@at2 + bias) * g2, full column in
// one block. 512 threads = 8 waves; wave w owns rows [w*64,w*64+64), n-tile 128.
// ---------------------------------------------------------------------------
__global__ __launch_bounds__(512, 2)
void gemm2_k(const ushort* __restrict__ A,      // Woutb [512][512] bf16
             const ushort* __restrict__ Bt,     // at2 [b][n][512] bf16
             const float* __restrict__ bias,
             const float* __restrict__ g2,
             float* __restrict__ outp)
{
    __shared__ __align__(16) ushort As[512 * 64];   // 64 KiB
    __shared__ __align__(16) ushort Bs[128 * 64];   // 16 KiB
    const int b  = blockIdx.y;
    const int n0 = blockIdx.x * 128;
    const int tid = threadIdx.x;
    const int w = tid >> 6, l = tid & 63;
    const int lq = l >> 4, lr = l & 15;
    const ushort* Bb = Bt + (size_t)b * N_ * 512;

    f32x4 acc[4][8];
    #pragma unroll
    for (int i = 0; i < 4; ++i)
        #pragma unroll
        for (int j = 0; j < 8; ++j)
            #pragma unroll
            for (int r = 0; r < 4; ++r) acc[i][j][r] = 0.f;

    for (int k0 = 0; k0 < 512; k0 += 64) {
        #pragma unroll
        for (int i = 0; i < 8; ++i) {
            int base = i * 512 + w * 64;           // wave-uniform chunk base
            int idx = base + l;
            int r = idx >> 3, ch = (idx & 7) ^ (r & 7);
            gload_lds16((const char*)A + (size_t)r * 1024 + k0 * 2 + ch * 16,
                        (char*)As + (size_t)base * 16);
        }
        #pragma unroll
        for (int i = 0; i < 2; ++i) {
            int base = i * 512 + w * 64;
            int idx = base + l;
            int r = idx >> 3, ch = (idx & 7) ^ (r & 7);
            gload_lds16((const char*)Bb + (size_t)(n0 + r) * 1024 + k0 * 2 + ch * 16,
                        (char*)Bs + (size_t)base * 16);
        }
        __syncthreads();
        #pragma unroll
        for (int kk = 0; kk < 2; ++kk) {
            bf16x8 af[4], bfr[8];
            #pragma unroll
            for (int mf = 0; mf < 4; ++mf) {
                int ra = w * 64 + mf * 16 + lr;
                int ch = (kk * 4 + lq) ^ (ra & 7);
                af[mf] = *(const bf16x8*)((const char*)As + ra * 128 + ch * 16);
            }
            #pragma unroll
            for (int nf = 0; nf < 8; ++nf) {
                int rb = nf * 16 + lr;
                int ch = (kk * 4 + lq) ^ (rb & 7);
                bfr[nf] = *(const bf16x8*)((const char*)Bs + rb * 128 + ch * 16);
            }
            #pragma unroll
            for (int mf = 0; mf < 4; ++mf)
                #pragma unroll
                for (int nf = 0; nf < 8; ++nf)
                    acc[mf][nf] = __builtin_amdgcn_mfma_f32_16x16x32_bf16(
                        af[mf], bfr[nf], acc[mf][nf], 0, 0, 0);
        }
        __syncthreads();
    }

    // epilogue: add bias, accumulate column sumsq, rms-norm, write final f32
    float4 bv[4], g2v[4];
    #pragma unroll
    for (int mf = 0; mf < 4; ++mf) {
        bv[mf]  = *reinterpret_cast<const float4*>(bias + w * 64 + mf * 16 + lq * 4);
        g2v[mf] = *reinterpret_cast<const float4*>(g2   + w * 64 + mf * 16 + lq * 4);
    }
    float csq[8] = {};
    #pragma unroll
    for (int mf = 0; mf < 4; ++mf)
        #pragma unroll
        for (int nf = 0; nf < 8; ++nf)
            #pragma unroll
            for (int r = 0; r < 4; ++r) {
                float wv = acc[mf][nf][r] + ((const float*)&bv[mf])[r];
                acc[mf][nf][r] = wv;
                csq[nf] += wv * wv;
            }
    #pragma unroll
    for (int nf = 0; nf < 8; ++nf) {
        csq[nf] += __shfl_xor(csq[nf], 16);
        csq[nf] += __shfl_xor(csq[nf], 32);
    }
    float* red  = (float*)As;       // 8 x 128 floats
    float* rs2s = red + 1024;       // 128 floats
    if (lq == 0) {
        #pragma unroll
        for (int nf = 0; nf < 8; ++nf)
            red[w * 128 + nf * 16 + lr] = csq[nf];
    }
    __syncthreads();
    if (tid < 128) {
        float s = 0.f;
        #pragma unroll
        for (int j = 0; j < 8; ++j) s += red[j * 128 + tid];
        rs2s[tid] = 22.627416998f / fmaxf(sqrtf(s), 1e-12f);
    }
    __syncthreads();
    #pragma unroll
    for (int nf = 0; nf < 8; ++nf) {
        const float rsv = rs2s[nf * 16 + lr];
        const int n = n0 + nf * 16 + lr;
        #pragma unroll
        for (int mf = 0; mf < 4; ++mf) {
            const int o = w * 64 + mf * 16 + lq * 4;
            float* p = outp + ((size_t)b * 512 + o) * N_ + n;
            #pragma unroll
            for (int r = 0; r < 4; ++r)
                p[(size_t)r * N_] = acc[mf][nf][r] * rsv * ((const float*)&g2v[mf])[r];
        }
    }
}

// ---------------------------------------------------------------------------
// row stats for k-softmax: per row (bh*64+d) of 4096 bf16 scores ->
// rowm = max, rowr = 1/sum(exp(v-max)).  One wave per row.
// ---------------------------------------------------------------------------
__global__ __launch_bounds__(256) void rowstat_k(const ushort* __restrict__ kk,
                                                 float* __restrict__ rowm,
                                                 float* __restrict__ rowr)
{
    const int row = blockIdx.x * 4 + (threadIdx.x >> 6);
    const int lane = threadIdx.x & 63;
    const ushort* p = kk + (size_t)row * N_;
    float vals[64];
    #pragma unroll
    for (int j = 0; j < 8; ++j) {
        ushort8_t u = *reinterpret_cast<const ushort8_t*>(p + lane * 8 + j * 512);
        #pragma unroll
        for (int t = 0; t < 8; ++t) vals[j * 8 + t] = bf2f(u[t]);
    }
    float mx = -1e30f;
    #pragma unroll
    for (int i = 0; i < 64; ++i) mx = fmaxf(mx, vals[i]);
    #pragma unroll
    for (int o = 32; o >= 1; o >>= 1) mx = fmaxf(mx, __shfl_xor(mx, o));
    float s = 0.f;
    #pragma unroll
    for (int i = 0; i < 64; ++i) s += __expf(vals[i] - mx);
    #pragma unroll
    for (int o = 32; o >= 1; o >>= 1) s += __shfl_xor(s, o);
    if (lane == 0) { rowm[row] = mx; rowr[row] = 1.f / s; }
}

// ---------------------------------------------------------------------------
// context partial: ctxp[bh*4+chunk][d][e] =
//   rowr[d] * sum_{n in chunk} exp(k[bh][d][n]-rowm[d]) * v[bh][e][n]
// ---------------------------------------------------------------------------
__global__ __launch_bounds__(256) void ctx_k(const ushort* __restrict__ kk,
                                             const ushort* __restrict__ vv,
                                             const float* __restrict__ rowm,
                                             const float* __restrict__ rowr,
                                             float* __restrict__ ctxp)
{
    const int bh = blockIdx.x, chunk = blockIdx.y;
    const ushort* kp = kk + (size_t)bh * 64 * N_;
    const ushort* vp = vv + (size_t)bh * 64 * N_;
    __shared__ float ks[64][129];
    __shared__ float vs[64][129];
    __shared__ float rm[64];
    const int tid = threadIdx.x;
    if (tid < 64) rm[tid] = rowm[(size_t)bh * 64 + tid];
    __syncthreads();
    const int td = tid >> 4, te = tid & 15;
    float acc[4][4] = {};
    for (int n0 = chunk * 1024; n0 < chunk * 1024 + 1024; n0 += 128) {
        #pragma unroll
        for (int i = 0; i < 32; ++i) {
            int idx = i * 256 + tid;
            int d = idx >> 7, nn = idx & 127;
            ks[d][nn] = __expf(bf2f(kp[(size_t)d * N_ + n0 + nn]) - rm[d]);
            vs[d][nn] = bf2f(vp[(size_t)d * N_ + n0 + nn]);
        }
        __syncthreads();
        for (int nn = 0; nn < 128; ++nn) {
            float a[4], bb[4];
            #pragma unroll
            for (int i = 0; i < 4; ++i) a[i]  = ks[td * 4 + i][nn];
            #pragma unroll
            for (int j = 0; j < 4; ++j) bb[j] = vs[te * 4 + j][nn];
            #pragma unroll
            for (int i = 0; i < 4; ++i)
                #pragma unroll
                for (int j = 0; j < 4; ++j)
                    acc[i][j] = fmaf(a[i], bb[j], acc[i][j]);
        }
        __syncthreads();
    }
    float rrv[4];
    #pragma unroll
    for (int i = 0; i < 4; ++i) rrv[i] = rowr[(size_t)bh * 64 + td * 4 + i];
    #pragma unroll
    for (int i = 0; i < 4; ++i)
        #pragma unroll
        for (int j = 0; j < 4; ++j)
            ctxp[((size_t)bh * 4 + chunk) * 4096 + (td * 4 + i) * 64 + te * 4 + j] =
                acc[i][j] * rrv[i];
}

// ---------------------------------------------------------------------------
// attn: at2[b][n][h*64+e] = bf16( sum_d ctx[bh][d][e] * q[bh][d][n] )
// ---------------------------------------------------------------------------
__global__ __launch_bounds__(256) void attn_k(const float* __restrict__ ctxp,
                                              const ushort* __restrict__ q,
                                              ushort* __restrict__ at2)
{
    const int bh = blockIdx.y;
    const int n0 = blockIdx.x * 256;
    __shared__ __align__(16) float ctx_s[64][64];
    __shared__ __align__(16) float q_s[64][256];
    const float* cp = ctxp + (size_t)bh * 4 * 4096;
    const ushort* qp = q + (size_t)bh * 64 * N_;
    const int tid = threadIdx.x;
    #pragma unroll
    for (int i = 0; i < 16; ++i) {
        int idx = i * 256 + tid;
        ctx_s[idx >> 6][idx & 63] = cp[idx] + cp[idx + 4096] + cp[idx + 8192] + cp[idx + 12288];
    }
    #pragma unroll 4
    for (int d = 0; d < 64; ++d)
        q_s[d][tid] = bf2f(qp[(size_t)d * N_ + n0 + tid]);
    __syncthreads();
    const int eg = tid >> 6;
    const int ng = tid & 63;
    float acc[16][4] = {};
    for (int d = 0; d < 64; ++d) {
        float qv[4];
        *(float4*)qv = *(float4*)&q_s[d][ng * 4];
        float cv[16];
        #pragma unroll
        for (int t = 0; t < 4; ++t)
            *(float4*)&cv[t * 4] = *(float4*)&ctx_s[d][eg * 16 + t * 4];
        #pragma unroll
        for (int e = 0; e < 16; ++e)
            #pragma unroll
            for (int j = 0; j < 4; ++j)
                acc[e][j] = fmaf(cv[e], qv[j], acc[e][j]);
    }
    const int b = bh >> 3, h = bh & 7;
    ushort* op = at2 + ((size_t)b * N_ + n0 + ng * 4) * 512 + h * 64 + eg * 16;
    #pragma unroll
    for (int j = 0; j < 4; ++j) {
        ushort4* pp = (ushort4*)(op + (size_t)j * 512);
        ushort4 u;
        u.x=f2bf(acc[0][j]);  u.y=f2bf(acc[1][j]);  u.z=f2bf(acc[2][j]);  u.w=f2bf(acc[3][j]);  pp[0]=u;
        u.x=f2bf(acc[4][j]);  u.y=f2bf(acc[5][j]);  u.z=f2bf(acc[6][j]);  u.w=f2bf(acc[7][j]);  pp[1]=u;
        u.x=f2bf(acc[8][j]);  u.y=f2bf(acc[9][j]);  u.z=f2bf(acc[10][j]); u.w=f2bf(acc[11][j]); pp[2]=u;
        u.x=f2bf(acc[12][j]); u.y=f2bf(acc[13][j]); u.z=f2bf(acc[14][j]); u.w=f2bf(acc[15][j]); pp[3]=u;
    }
}

// ---------------------------------------------------------------------------
extern "C" void kernel_launch(void* const* d_in, const int* in_sizes, int n_in,
                              void* d_out, int out_size, void* d_ws, size_t ws_size,
                              hipStream_t stream)
{
    const float* x    = (const float*)d_in[0];
    const float* g1   = (const float*)d_in[1];
    const float* Wqkv = (const float*)d_in[2];
    const float* Wout = (const float*)d_in[3];
    const float* bout = (const float*)d_in[4];
    const float* g2   = (const float*)d_in[5];
    float* out = (float*)d_out;

    // ws layout (<= 258.25 MiB):
    //   [0,64Mi)     qbuf bf16        (csq1 f32 2Mi aliased here pre-GEMM1)
    //   [64,128Mi)   kbuf bf16        -> at2 bf16 after ctx_k
    //   [128,192Mi)  vbuf bf16
    //   [192,256Mi)  Xt bf16          -> after GEMM1: ctxp f32 (8Mi) @192,
    //                                    rowm/rowr @200Mi
    //   [256Mi..)    Wqkvb(1.5Mi) Woutb(0.5Mi) rs1(256Ki)
    char* wsb = (char*)d_ws;
    ushort* qbuf  = (ushort*)wsb;
    float*  csq1  = (float*)wsb;     // alias (dead once rs1 computed)
    ushort* kbuf  = (ushort*)(wsb + ((size_t)64 << 20));
    ushort* vbuf  = (ushort*)(wsb + ((size_t)128 << 20));
    ushort* Xt    = (ushort*)(wsb + ((size_t)192 << 20));
    float*  ctxp  = (float*)Xt;
    float*  rowm  = (float*)(wsb + ((size_t)200 << 20));
    float*  rowr  = rowm + 8192;
    char*   tail  = wsb + ((size_t)256 << 20);
    ushort* Wqkvb = (ushort*)tail;
    ushort* Woutb = (ushort*)(tail + (size_t)1536 * 512 * 2);
    float*  rs1   = (float*)(tail + (size_t)1536 * 512 * 2 + (size_t)512 * 512 * 2);
    ushort* at2   = kbuf;   // alias: k dead after ctx_k

    // 1. weight prep (bf16; g1 folded into Wqkv)
    wprep_k<<<768, 256, 0, stream>>>(Wqkv, g1, Wqkvb, 1536 * 512 / 4);
    wprep_k<<<256, 256, 0, stream>>>(Wout, nullptr, Woutb, 512 * 512 / 4);
    // 2. Xt[b][n][c] = bf16(x^T) + column sumsq partials
    transpose_k<<<dim3(64, 8, 16), 256, 0, stream>>>(x, Xt, csq1);
    // 3. rs1 = sqrt(512)/||x_col||
    rs1_reduce_k<<<256, 256, 0, stream>>>(csq1, rs1);
    // 4. QKV GEMM (256x256, per-phase interleave): q(softmaxed), k, v (bf16)
    mfma_gemm<<<dim3(16, 6, B_), 512, 0, stream>>>(Wqkvb, Xt, rs1,
                                                   qbuf, kbuf, vbuf);
    // 5. k row stats (max, 1/sum-exp)
    rowstat_k<<<2048, 256, 0, stream>>>(kbuf, rowm, rowr);
    // 6. context partials (softmax applied on the fly)
    ctx_k<<<dim3(B_ * 8, 4), 256, 0, stream>>>(kbuf, vbuf, rowm, rowr, ctxp);
    // 7. attn -> at2 bf16 [b][n][hid]
    attn_k<<<dim3(N_ / 256, B_ * 8), 256, 0, stream>>>(ctxp, qbuf, at2);
    // 8. output GEMM + bias + full rms-norm fused -> d_out f32 (final)
    gemm2_k<<<dim3(32, B_), 512, 0, stream>>>(Woutb, at2, bout, g2, out);
}

// Round 7
// 339.588 us; speedup vs baseline: 1.3128x; 1.3128x over previous
//
#include <hip/hip_runtime.h>
#include <hip/hip_bf16.h>
#include <math.h>

#define B_ 16
#define C_ 512
#define N_ 4096
#define NCOL (B_ * N_)  // 65536 columns (b, hw)

typedef short bf16x8 __attribute__((ext_vector_type(8)));
typedef ushort ushort8_t __attribute__((ext_vector_type(8)));
typedef float f32x4 __attribute__((ext_vector_type(4)));

__device__ __forceinline__ ushort f2bf(float f) {
    unsigned u = __float_as_uint(f);
    unsigned r = (u + 0x7FFFu + ((u >> 16) & 1u)) >> 16;
    return (ushort)r;
}
__device__ __forceinline__ float bf2f(ushort u) {
    return __uint_as_float((unsigned)u << 16);
}
__device__ __forceinline__ void gload_lds16(const void* g, void* l) {
    __builtin_amdgcn_global_load_lds(
        (const __attribute__((address_space(1))) unsigned int*)g,
        (__attribute__((address_space(3))) unsigned int*)l, 16, 0, 0);
}

// ---------------------------------------------------------------------------
// weight prep: Wb[i] = bf16(W[i] * g[c])  (g optional, c = flat%512)
// ---------------------------------------------------------------------------
__global__ __launch_bounds__(256) void wprep_k(const float* __restrict__ W,
                                               const float* __restrict__ g,
                                               ushort* __restrict__ Wb, int nvec)
{
    int i = blockIdx.x * 256 + threadIdx.x;
    if (i >= nvec) return;
    float4 wv = reinterpret_cast<const float4*>(W)[i];
    if (g) {
        const float4 gv = *reinterpret_cast<const float4*>(g + ((i * 4) & 511));
        wv.x *= gv.x; wv.y *= gv.y; wv.z *= gv.z; wv.w *= gv.w;
    }
    ushort4 u;
    u.x = f2bf(wv.x); u.y = f2bf(wv.y); u.z = f2bf(wv.z); u.w = f2bf(wv.w);
    reinterpret_cast<ushort4*>(Wb)[i] = u;
}

// ---------------------------------------------------------------------------
// transpose+convert+colnorm-partial:
//   Xt[b][n][c] = bf16(x[b][c][n]);  csq1[ctile][b*4096+n] += sum_c x^2
// ---------------------------------------------------------------------------
__global__ __launch_bounds__(256) void transpose_k(const float* __restrict__ X,
                                                   ushort* __restrict__ Xt,
                                                   float* __restrict__ csq1)
{
    __shared__ float t[64][65];
    __shared__ float sq[4][64];
    const int b = blockIdx.z, n0 = blockIdx.x * 64, c0 = blockIdx.y * 64;
    const int tid = threadIdx.x;
    const int tx = tid & 63, ty = tid >> 6;
    const float* xp = X + ((size_t)b * C_ + c0) * N_ + n0;
    float local = 0.f;
    #pragma unroll
    for (int i = 0; i < 16; ++i) {
        float v = xp[(size_t)(ty + 4 * i) * N_ + tx];
        t[ty + 4 * i][tx] = v;
        local += v * v;
    }
    sq[ty][tx] = local;
    __syncthreads();
    #pragma unroll
    for (int i = 0; i < 4; ++i) {
        int nl = (tid >> 4) + i * 16;
        int cl = (tid & 15) * 4;
        ushort4 u;
        u.x = f2bf(t[cl + 0][nl]);
        u.y = f2bf(t[cl + 1][nl]);
        u.z = f2bf(t[cl + 2][nl]);
        u.w = f2bf(t[cl + 3][nl]);
        *reinterpret_cast<ushort4*>(Xt + ((size_t)b * N_ + n0 + nl) * 512 + c0 + cl) = u;
    }
    if (tid < 64)
        csq1[(size_t)blockIdx.y * NCOL + (size_t)b * N_ + n0 + tid] =
            sq[0][tid] + sq[1][tid] + sq[2][tid] + sq[3][tid];
}

// ---------------------------------------------------------------------------
// reduce 8 csq1 partials -> rs1 = sqrt(512)/max(||x_col||, eps)
// ---------------------------------------------------------------------------
__global__ __launch_bounds__(256) void rs1_reduce_k(const float* __restrict__ csq1,
                                                    float* __restrict__ rs1)
{
    int col = blockIdx.x * 256 + threadIdx.x;
    float s = 0.f;
    #pragma unroll
    for (int j = 0; j < 8; ++j) s += csq1[(size_t)j * NCOL + col];
    rs1[col] = 22.627416998f / fmaxf(sqrtf(s), 1e-12f);
}

// ---------------------------------------------------------------------------
// MFMA GEMM1 (256x256 tile, 8 waves 2x4, BK=64, double-buffered LDS,
// per-phase interleave + counted vmcnt):  acc[o][n] = sum_c A[o][c]*Bt[b][n][c]
// Epilogue: acc *= rs1[b][n];
//   part 0 (q): softmax over d * 0.125 -> qT[bh][n][64] bf16 (8B packed stores)
//   part 1/2 (k/v): -> bf16 raw [bh*64+d][n]
// ---------------------------------------------------------------------------
__global__ __launch_bounds__(512, 2)
void mfma_gemm(const ushort* __restrict__ A, const ushort* __restrict__ Bt,
               const float* __restrict__ rs1,
               ushort* __restrict__ qT, ushort* __restrict__ kd,
               ushort* __restrict__ vd)
{
    // lds[buf][A/B][256 rows][8 chunks][16B]
    __shared__ __align__(16) char lds[2][2][32768];
    const int b  = blockIdx.z;
    const int n0 = blockIdx.x * 256;
    const int m0 = blockIdx.y * 256;
    const int tid = threadIdx.x;
    const int w = tid >> 6, l = tid & 63;
    const int wm = w >> 2, wn = w & 3;          // 2 x 4 waves
    const int lq = l >> 4, lr = l & 15;
    const ushort* Bb = Bt + (size_t)b * N_ * 512;

    f32x4 acc[8][4];
    #pragma unroll
    for (int i = 0; i < 8; ++i)
        #pragma unroll
        for (int j = 0; j < 4; ++j)
            #pragma unroll
            for (int r = 0; r < 4; ++r) acc[i][j][r] = 0.f;

#define STAGE_STEP(t, i)                                                      \
    do {                                                                      \
        const int kb_ = (t) * 128;                                            \
        const int idx_ = (i) * 512 + tid;                                     \
        const int r_ = idx_ >> 3;                                             \
        const int ch_ = (idx_ & 7) ^ (r_ & 7);                                \
        gload_lds16((const char*)A + (size_t)(m0 + r_) * 1024 + kb_ + ch_ * 16,\
                    &lds[(t) & 1][0][idx_ * 16]);                             \
        gload_lds16((const char*)Bb + (size_t)(n0 + r_) * 1024 + kb_ + ch_ * 16,\
                    &lds[(t) & 1][1][idx_ * 16]);                             \
    } while (0)

    #pragma unroll
    for (int i = 0; i < 4; ++i) STAGE_STEP(0, i);

    bf16x8 bfr[4];
    #pragma unroll 2
    for (int t = 0; t < 8; ++t) {
        const char* As = lds[t & 1][0];
        const char* Bs = lds[t & 1][1];
        #pragma unroll
        for (int ph = 0; ph < 4; ++ph) {
            const int kk = ph >> 1, mg = ph & 1;
            bf16x8 af[4];
            if (ph != 0) {
                #pragma unroll
                for (int m2 = 0; m2 < 4; ++m2) {
                    int ra = wm * 128 + (mg * 4 + m2) * 16 + lr;
                    int ch = (kk * 4 + lq) ^ (ra & 7);
                    af[m2] = *(const bf16x8*)(As + ra * 128 + ch * 16);
                }
                if (mg == 0) {
                    #pragma unroll
                    for (int nf = 0; nf < 4; ++nf) {
                        int rb = wn * 64 + nf * 16 + lr;
                        int ch = (kk * 4 + lq) ^ (rb & 7);
                        bfr[nf] = *(const bf16x8*)(Bs + rb * 128 + ch * 16);
                    }
                }
            }
            if (t < 7) STAGE_STEP(t + 1, ph);
            if (ph == 0) {
                if (t < 7) { asm volatile("s_waitcnt vmcnt(2)" ::: "memory"); }
                else       { asm volatile("s_waitcnt vmcnt(0)" ::: "memory"); }
            }
            __builtin_amdgcn_s_barrier();
            if (ph == 0) {
                #pragma unroll
                for (int m2 = 0; m2 < 4; ++m2) {
                    int ra = wm * 128 + m2 * 16 + lr;
                    int ch = lq ^ (ra & 7);
                    af[m2] = *(const bf16x8*)(As + ra * 128 + ch * 16);
                }
                #pragma unroll
                for (int nf = 0; nf < 4; ++nf) {
                    int rb = wn * 64 + nf * 16 + lr;
                    int ch = lq ^ (rb & 7);
                    bfr[nf] = *(const bf16x8*)(Bs + rb * 128 + ch * 16);
                }
            }
            asm volatile("s_waitcnt lgkmcnt(0)" ::: "memory");
            __builtin_amdgcn_sched_barrier(0);
            __builtin_amdgcn_s_setprio(1);
            #pragma unroll
            for (int m2 = 0; m2 < 4; ++m2)
                #pragma unroll
                for (int nf = 0; nf < 4; ++nf)
                    acc[mg * 4 + m2][nf] = __builtin_amdgcn_mfma_f32_16x16x32_bf16(
                        af[m2], bfr[nf], acc[mg * 4 + m2][nf], 0, 0, 0);
            __builtin_amdgcn_s_setprio(0);
            __builtin_amdgcn_s_barrier();
        }
    }
#undef STAGE_STEP

    const int part = m0 >> 9;                       // block-uniform (0/1/2)
    const int mloc = (m0 & 511) + wm * 128;         // 0/128/256/384 within part
    const int nbase = n0 + wn * 64;
    if (part == 0) {
        // q: *rs1, softmax over the 64 d-rows of each head, *0.125,
        // write qT[bh][n][64] bf16 with packed 8B stores.
        #pragma unroll
        for (int hg = 0; hg < 2; ++hg) {
            const int head = (mloc >> 6) + hg;
            #pragma unroll
            for (int nf = 0; nf < 4; ++nf) {
                const int n = nbase + nf * 16 + lr;
                const float sc = rs1[(size_t)b * N_ + n];
                float v[4][4];
                float mx = -1e30f;
                #pragma unroll
                for (int m2 = 0; m2 < 4; ++m2)
                    #pragma unroll
                    for (int r = 0; r < 4; ++r) {
                        v[m2][r] = acc[hg * 4 + m2][nf][r] * sc;
                        mx = fmaxf(mx, v[m2][r]);
                    }
                mx = fmaxf(mx, __shfl_xor(mx, 16));
                mx = fmaxf(mx, __shfl_xor(mx, 32));
                float s = 0.f;
                #pragma unroll
                for (int m2 = 0; m2 < 4; ++m2)
                    #pragma unroll
                    for (int r = 0; r < 4; ++r) {
                        v[m2][r] = __expf(v[m2][r] - mx);
                        s += v[m2][r];
                    }
                s += __shfl_xor(s, 16);
                s += __shfl_xor(s, 32);
                const float r8 = 0.125f / s;
                ushort* qp = qT + (((size_t)b * 8 + head) * N_ + n) * 64;
                #pragma unroll
                for (int m2 = 0; m2 < 4; ++m2) {
                    ushort4 u;
                    u.x = f2bf(v[m2][0] * r8);
                    u.y = f2bf(v[m2][1] * r8);
                    u.z = f2bf(v[m2][2] * r8);
                    u.w = f2bf(v[m2][3] * r8);
                    *reinterpret_cast<ushort4*>(qp + m2 * 16 + lq * 4) = u;
                }
            }
        }
    } else {
        ushort* dst = (part == 1) ? kd : vd;
        #pragma unroll
        for (int nf = 0; nf < 4; ++nf) {
            const int n = nbase + nf * 16 + lr;
            const float sc = rs1[(size_t)b * N_ + n];
            #pragma unroll
            for (int mf = 0; mf < 8; ++mf) {
                const int o = mloc + mf * 16 + lq * 4;
                #pragma unroll
                for (int r = 0; r < 4; ++r)
                    dst[((size_t)b * 512 + o + r) * N_ + n] =
                        f2bf(acc[mf][nf][r] * sc);
            }
        }
    }
}

// ---------------------------------------------------------------------------
// GEMM2 fused: out[b][o][n] = rmsnorm(Wout@at2 + bias) * g2, full column in
// one block. 512 threads = 8 waves; wave w owns rows [w*64,w*64+64), n-tile 128.
// ---------------------------------------------------------------------------
__global__ __launch_bounds__(512, 2)
void gemm2_k(const ushort* __restrict__ A,      // Woutb [512][512] bf16
             const ushort* __restrict__ Bt,     // at2 [b][n][512] bf16
             const float* __restrict__ bias,
             const float* __restrict__ g2,
             float* __restrict__ outp)
{
    __shared__ __align__(16) ushort As[512 * 64];   // 64 KiB
    __shared__ __align__(16) ushort Bs[128 * 64];   // 16 KiB
    const int b  = blockIdx.y;
    const int n0 = blockIdx.x * 128;
    const int tid = threadIdx.x;
    const int w = tid >> 6, l = tid & 63;
    const int lq = l >> 4, lr = l & 15;
    const ushort* Bb = Bt + (size_t)b * N_ * 512;

    f32x4 acc[4][8];
    #pragma unroll
    for (int i = 0; i < 4; ++i)
        #pragma unroll
        for (int j = 0; j < 8; ++j)
            #pragma unroll
            for (int r = 0; r < 4; ++r) acc[i][j][r] = 0.f;

    for (int k0 = 0; k0 < 512; k0 += 64) {
        #pragma unroll
        for (int i = 0; i < 8; ++i) {
            int base = i * 512 + w * 64;           // wave-uniform chunk base
            int idx = base + l;
            int r = idx >> 3, ch = (idx & 7) ^ (r & 7);
            gload_lds16((const char*)A + (size_t)r * 1024 + k0 * 2 + ch * 16,
                        (char*)As + (size_t)base * 16);
        }
        #pragma unroll
        for (int i = 0; i < 2; ++i) {
            int base = i * 512 + w * 64;
            int idx = base + l;
            int r = idx >> 3, ch = (idx & 7) ^ (r & 7);
            gload_lds16((const char*)Bb + (size_t)(n0 + r) * 1024 + k0 * 2 + ch * 16,
                        (char*)Bs + (size_t)base * 16);
        }
        __syncthreads();
        #pragma unroll
        for (int kk = 0; kk < 2; ++kk) {
            bf16x8 af[4], bfr[8];
            #pragma unroll
            for (int mf = 0; mf < 4; ++mf) {
                int ra = w * 64 + mf * 16 + lr;
                int ch = (kk * 4 + lq) ^ (ra & 7);
                af[mf] = *(const bf16x8*)((const char*)As + ra * 128 + ch * 16);
            }
            #pragma unroll
            for (int nf = 0; nf < 8; ++nf) {
                int rb = nf * 16 + lr;
                int ch = (kk * 4 + lq) ^ (rb & 7);
                bfr[nf] = *(const bf16x8*)((const char*)Bs + rb * 128 + ch * 16);
            }
            #pragma unroll
            for (int mf = 0; mf < 4; ++mf)
                #pragma unroll
                for (int nf = 0; nf < 8; ++nf)
                    acc[mf][nf] = __builtin_amdgcn_mfma_f32_16x16x32_bf16(
                        af[mf], bfr[nf], acc[mf][nf], 0, 0, 0);
        }
        __syncthreads();
    }

    // epilogue: add bias, accumulate column sumsq, rms-norm, write final f32
    float4 bv[4], g2v[4];
    #pragma unroll
    for (int mf = 0; mf < 4; ++mf) {
        bv[mf]  = *reinterpret_cast<const float4*>(bias + w * 64 + mf * 16 + lq * 4);
        g2v[mf] = *reinterpret_cast<const float4*>(g2   + w * 64 + mf * 16 + lq * 4);
    }
    float csq[8] = {};
    #pragma unroll
    for (int mf = 0; mf < 4; ++mf)
        #pragma unroll
        for (int nf = 0; nf < 8; ++nf)
            #pragma unroll
            for (int r = 0; r < 4; ++r) {
                float wv = acc[mf][nf][r] + ((const float*)&bv[mf])[r];
                acc[mf][nf][r] = wv;
                csq[nf] += wv * wv;
            }
    #pragma unroll
    for (int nf = 0; nf < 8; ++nf) {
        csq[nf] += __shfl_xor(csq[nf], 16);
        csq[nf] += __shfl_xor(csq[nf], 32);
    }
    float* red  = (float*)As;       // 8 x 128 floats
    float* rs2s = red + 1024;       // 128 floats
    if (lq == 0) {
        #pragma unroll
        for (int nf = 0; nf < 8; ++nf)
            red[w * 128 + nf * 16 + lr] = csq[nf];
    }
    __syncthreads();
    if (tid < 128) {
        float s = 0.f;
        #pragma unroll
        for (int j = 0; j < 8; ++j) s += red[j * 128 + tid];
        rs2s[tid] = 22.627416998f / fmaxf(sqrtf(s), 1e-12f);
    }
    __syncthreads();
    #pragma unroll
    for (int nf = 0; nf < 8; ++nf) {
        const float rsv = rs2s[nf * 16 + lr];
        const int n = n0 + nf * 16 + lr;
        #pragma unroll
        for (int mf = 0; mf < 4; ++mf) {
            const int o = w * 64 + mf * 16 + lq * 4;
            float* p = outp + ((size_t)b * 512 + o) * N_ + n;
            #pragma unroll
            for (int r = 0; r < 4; ++r)
                p[(size_t)r * N_] = acc[mf][nf][r] * rsv * ((const float*)&g2v[mf])[r];
        }
    }
}

// ---------------------------------------------------------------------------
// row stats for k-softmax: per row (bh*64+d) of 4096 bf16 scores ->
// rowm = max, rowr = 1/sum(exp(v-max)).  One wave per row.
// ---------------------------------------------------------------------------
__global__ __launch_bounds__(256) void rowstat_k(const ushort* __restrict__ kk,
                                                 float* __restrict__ rowm,
                                                 float* __restrict__ rowr)
{
    const int row = blockIdx.x * 4 + (threadIdx.x >> 6);
    const int lane = threadIdx.x & 63;
    const ushort* p = kk + (size_t)row * N_;
    float vals[64];
    #pragma unroll
    for (int j = 0; j < 8; ++j) {
        ushort8_t u = *reinterpret_cast<const ushort8_t*>(p + lane * 8 + j * 512);
        #pragma unroll
        for (int t = 0; t < 8; ++t) vals[j * 8 + t] = bf2f(u[t]);
    }
    float mx = -1e30f;
    #pragma unroll
    for (int i = 0; i < 64; ++i) mx = fmaxf(mx, vals[i]);
    #pragma unroll
    for (int o = 32; o >= 1; o >>= 1) mx = fmaxf(mx, __shfl_xor(mx, o));
    float s = 0.f;
    #pragma unroll
    for (int i = 0; i < 64; ++i) s += __expf(vals[i] - mx);
    #pragma unroll
    for (int o = 32; o >= 1; o >>= 1) s += __shfl_xor(s, o);
    if (lane == 0) { rowm[row] = mx; rowr[row] = 1.f / s; }
}

// ---------------------------------------------------------------------------
// ctx (MFMA): ctxp[bh][chunk][e][d] = rowr[d] *
//     sum_{n in chunk} v[bh][e][n] * exp(k[bh][d][n]-rowm[d])
// A = v rows (e), B = exp(k) rows (d), K = n (1024 per chunk, 128/subtile).
// kx reg-staged with fused exp; vx via global_load_lds, both XOR-swizzled
// (16 chunks/row: ch ^= row&15).
// ---------------------------------------------------------------------------
__global__ __launch_bounds__(256) void ctx_k(const ushort* __restrict__ kk,
                                             const ushort* __restrict__ vv,
                                             const float* __restrict__ rowm,
                                             const float* __restrict__ rowr,
                                             float* __restrict__ ctxp)
{
    const int bh = blockIdx.x, chunk = blockIdx.y;
    const ushort* kp = kk + (size_t)bh * 64 * N_;
    const ushort* vp = vv + (size_t)bh * 64 * N_;
    __shared__ __align__(16) ushort kx[64 * 128];   // 16 KiB
    __shared__ __align__(16) ushort vx[64 * 128];   // 16 KiB
    __shared__ float rm[64];
    const int tid = threadIdx.x;
    const int w = tid >> 6, l = tid & 63;
    const int lq = l >> 4, lr = l & 15;
    const int we = w >> 1, wd = w & 1;              // e-half, d-half of 64x64
    if (tid < 64) rm[tid] = rowm[(size_t)bh * 64 + tid];
    __syncthreads();

    f32x4 acc[2][2];
    #pragma unroll
    for (int i = 0; i < 2; ++i)
        #pragma unroll
        for (int j = 0; j < 2; ++j)
            #pragma unroll
            for (int r = 0; r < 4; ++r) acc[i][j][r] = 0.f;

    for (int s = 0; s < 8; ++s) {
        const int n0 = chunk * 1024 + s * 128;
        // v: direct to LDS, source chunk pre-swizzled
        #pragma unroll
        for (int i = 0; i < 4; ++i) {
            int idx = i * 256 + tid;
            int row = idx >> 4;
            int ch  = (idx & 15) ^ (row & 15);
            gload_lds16((const char*)(vp + (size_t)row * N_ + n0 + ch * 8),
                        (char*)vx + idx * 16);
        }
        // k: reg-stage + exp + swizzled ds_write
        #pragma unroll
        for (int i = 0; i < 4; ++i) {
            int idx = i * 256 + tid;
            int row = idx >> 4;
            int ch  = idx & 15;
            ushort8_t u = *reinterpret_cast<const ushort8_t*>(
                kp + (size_t)row * N_ + n0 + ch * 8);
            float m_ = rm[row];
            ushort8_t o;
            #pragma unroll
            for (int t = 0; t < 8; ++t) o[t] = f2bf(__expf(bf2f(u[t]) - m_));
            *(ushort8_t*)((char*)kx + (row * 16 + (ch ^ (row & 15))) * 16) = o;
        }
        __syncthreads();
        #pragma unroll
        for (int k2 = 0; k2 < 4; ++k2) {
            bf16x8 af[2], bfr[2];
            #pragma unroll
            for (int i = 0; i < 2; ++i) {
                int re = we * 32 + i * 16 + lr;
                int cha = (k2 * 4 + lq) ^ (re & 15);
                af[i] = *(const bf16x8*)((const char*)vx + (re * 16 + cha) * 16);
                int rd = wd * 32 + i * 16 + lr;
                int chb = (k2 * 4 + lq) ^ (rd & 15);
                bfr[i] = *(const bf16x8*)((const char*)kx + (rd * 16 + chb) * 16);
            }
            #pragma unroll
            for (int i = 0; i < 2; ++i)
                #pragma unroll
                for (int j = 0; j < 2; ++j)
                    acc[i][j] = __builtin_amdgcn_mfma_f32_16x16x32_bf16(
                        af[i], bfr[j], acc[i][j], 0, 0, 0);
        }
        __syncthreads();
    }
    // write ctxp[bh][chunk][e][d], scale by rowr[d]
    float* cbase = ctxp + ((size_t)bh * 4 + chunk) * 4096;
    #pragma unroll
    for (int j = 0; j < 2; ++j) {
        const int d = wd * 32 + j * 16 + lr;
        const float rr = rowr[(size_t)bh * 64 + d];
        #pragma unroll
        for (int i = 0; i < 2; ++i) {
            const int e = we * 32 + i * 16 + lq * 4;
            #pragma unroll
            for (int r = 0; r < 4; ++r)
                cbase[(size_t)(e + r) * 64 + d] = acc[i][j][r] * rr;
        }
    }
}

// ---------------------------------------------------------------------------
// attn (MFMA): at2[b][n][h*64+e] = bf16( sum_d ctx[e][d] * qT[bh][n][d] )
// A = ctx_s rows (e), B = qT rows (n), K = d (64). ctx partials summed into
// swizzled LDS; qT staged via global_load_lds (pre-swizzled source).
// ---------------------------------------------------------------------------
__global__ __launch_bounds__(256) void attn_k(const float* __restrict__ ctxp,
                                              const ushort* __restrict__ qT,
                                              ushort* __restrict__ at2)
{
    const int bh = blockIdx.y;
    const int n0 = blockIdx.x * 256;
    const int b = bh >> 3, h = bh & 7;
    __shared__ __align__(16) ushort qx[256 * 64];   // 32 KiB
    __shared__ __align__(16) ushort cx[64 * 64];    // 8 KiB
    const int tid = threadIdx.x;
    const int w = tid >> 6, l = tid & 63;
    const int lq = l >> 4, lr = l & 15;
    const ushort* qp = qT + ((size_t)bh * N_ + n0) * 64;

    // stage qT tile [256][64] (8 chunks/row, ch ^= row&7)
    #pragma unroll
    for (int i = 0; i < 8; ++i) {
        int idx = i * 256 + tid;
        int row = idx >> 3;
        int ch  = (idx & 7) ^ (row & 7);
        gload_lds16((const char*)(qp + (size_t)row * 64 + ch * 8),
                    (char*)qx + idx * 16);
    }
    // build ctx_s: sum 4 chunk-partials, -> bf16, swizzled write
    {
        const float* cp = ctxp + (size_t)bh * 4 * 4096;
        const int e = tid >> 2, db = (tid & 3) * 16;
        float vs[16];
        #pragma unroll
        for (int t = 0; t < 4; ++t) {
            float4 a0 = *(const float4*)(cp + e * 64 + db + t * 4);
            float4 a1 = *(const float4*)(cp + 4096 + e * 64 + db + t * 4);
            float4 a2 = *(const float4*)(cp + 8192 + e * 64 + db + t * 4);
            float4 a3 = *(const float4*)(cp + 12288 + e * 64 + db + t * 4);
            vs[t * 4 + 0] = a0.x + a1.x + a2.x + a3.x;
            vs[t * 4 + 1] = a0.y + a1.y + a2.y + a3.y;
            vs[t * 4 + 2] = a0.z + a1.z + a2.z + a3.z;
            vs[t * 4 + 3] = a0.w + a1.w + a2.w + a3.w;
        }
        ushort8_t o0, o1;
        #pragma unroll
        for (int t = 0; t < 8; ++t) { o0[t] = f2bf(vs[t]); o1[t] = f2bf(vs[8 + t]); }
        const int c0 = (db >> 3) ^ (e & 7);
        const int c1 = ((db >> 3) + 1) ^ (e & 7);
        *(ushort8_t*)((char*)cx + (e * 8 + c0) * 16) = o0;
        *(ushort8_t*)((char*)cx + (e * 8 + c1) * 16) = o1;
    }
    __syncthreads();

    f32x4 acc[4][4];
    #pragma unroll
    for (int i = 0; i < 4; ++i)
        #pragma unroll
        for (int j = 0; j < 4; ++j)
            #pragma unroll
            for (int r = 0; r < 4; ++r) acc[i][j][r] = 0.f;

    #pragma unroll
    for (int k2 = 0; k2 < 2; ++k2) {
        bf16x8 af[4], bfr[4];
        #pragma unroll
        for (int et = 0; et < 4; ++et) {
            int re = et * 16 + lr;
            int ch = (k2 * 4 + lq) ^ (re & 7);
            af[et] = *(const bf16x8*)((const char*)cx + (re * 8 + ch) * 16);
        }
        #pragma unroll
        for (int nt = 0; nt < 4; ++nt) {
            int rn = w * 64 + nt * 16 + lr;
            int ch = (k2 * 4 + lq) ^ (rn & 7);
            bfr[nt] = *(const bf16x8*)((const char*)qx + (rn * 8 + ch) * 16);
        }
        #pragma unroll
        for (int et = 0; et < 4; ++et)
            #pragma unroll
            for (int nt = 0; nt < 4; ++nt)
                acc[et][nt] = __builtin_amdgcn_mfma_f32_16x16x32_bf16(
                    af[et], bfr[nt], acc[et][nt], 0, 0, 0);
    }
    // store: rows e = et*16+lq*4+r, cols n = w*64+nt*16+lr; pack r -> 8B
    #pragma unroll
    for (int nt = 0; nt < 4; ++nt) {
        const int n = n0 + w * 64 + nt * 16 + lr;
        ushort* op = at2 + ((size_t)b * N_ + n) * 512 + h * 64;
        #pragma unroll
        for (int et = 0; et < 4; ++et) {
            ushort4 u;
            u.x = f2bf(acc[et][nt][0]);
            u.y = f2bf(acc[et][nt][1]);
            u.z = f2bf(acc[et][nt][2]);
            u.w = f2bf(acc[et][nt][3]);
            *reinterpret_cast<ushort4*>(op + et * 16 + lq * 4) = u;
        }
    }
}

// ---------------------------------------------------------------------------
extern "C" void kernel_launch(void* const* d_in, const int* in_sizes, int n_in,
                              void* d_out, int out_size, void* d_ws, size_t ws_size,
                              hipStream_t stream)
{
    const float* x    = (const float*)d_in[0];
    const float* g1   = (const float*)d_in[1];
    const float* Wqkv = (const float*)d_in[2];
    const float* Wout = (const float*)d_in[3];
    const float* bout = (const float*)d_in[4];
    const float* g2   = (const float*)d_in[5];
    float* out = (float*)d_out;

    // ws layout (<= 258.25 MiB):
    //   [0,64Mi)     qT bf16 [bh][n][64]  (csq1 f32 2Mi aliased pre-GEMM1)
    //   [64,128Mi)   kbuf bf16            -> at2 bf16 after ctx_k
    //   [128,192Mi)  vbuf bf16
    //   [192,256Mi)  Xt bf16              -> after GEMM1: ctxp f32 (8Mi) @192,
    //                                       rowm/rowr @200Mi
    //   [256Mi..)    Wqkvb(1.5Mi) Woutb(0.5Mi) rs1(256Ki)
    char* wsb = (char*)d_ws;
    ushort* qbuf  = (ushort*)wsb;
    float*  csq1  = (float*)wsb;     // alias (dead once rs1 computed)
    ushort* kbuf  = (ushort*)(wsb + ((size_t)64 << 20));
    ushort* vbuf  = (ushort*)(wsb + ((size_t)128 << 20));
    ushort* Xt    = (ushort*)(wsb + ((size_t)192 << 20));
    float*  ctxp  = (float*)Xt;
    float*  rowm  = (float*)(wsb + ((size_t)200 << 20));
    float*  rowr  = rowm + 8192;
    char*   tail  = wsb + ((size_t)256 << 20);
    ushort* Wqkvb = (ushort*)tail;
    ushort* Woutb = (ushort*)(tail + (size_t)1536 * 512 * 2);
    float*  rs1   = (float*)(tail + (size_t)1536 * 512 * 2 + (size_t)512 * 512 * 2);
    ushort* at2   = kbuf;   // alias: k dead after ctx_k

    // 1. weight prep (bf16; g1 folded into Wqkv)
    wprep_k<<<768, 256, 0, stream>>>(Wqkv, g1, Wqkvb, 1536 * 512 / 4);
    wprep_k<<<256, 256, 0, stream>>>(Wout, nullptr, Woutb, 512 * 512 / 4);
    // 2. Xt[b][n][c] = bf16(x^T) + column sumsq partials
    transpose_k<<<dim3(64, 8, 16), 256, 0, stream>>>(x, Xt, csq1);
    // 3. rs1 = sqrt(512)/||x_col||
    rs1_reduce_k<<<256, 256, 0, stream>>>(csq1, rs1);
    // 4. QKV GEMM: qT (softmaxed, transposed), k, v (bf16)
    mfma_gemm<<<dim3(16, 6, B_), 512, 0, stream>>>(Wqkvb, Xt, rs1,
                                                   qbuf, kbuf, vbuf);
    // 5. k row stats (max, 1/sum-exp)
    rowstat_k<<<2048, 256, 0, stream>>>(kbuf, rowm, rowr);
    // 6. context partials (MFMA, softmax applied on the fly) -> ctxp[e][d]
    ctx_k<<<dim3(B_ * 8, 4), 256, 0, stream>>>(kbuf, vbuf, rowm, rowr, ctxp);
    // 7. attn (MFMA) -> at2 bf16 [b][n][hid]
    attn_k<<<dim3(N_ / 256, B_ * 8), 256, 0, stream>>>(ctxp, qbuf, at2);
    // 8. output GEMM + bias + full rms-norm fused -> d_out f32 (final)
    gemm2_k<<<dim3(32, B_), 512, 0, stream>>>(Woutb, at2, bout, g2, out);
}

// Round 8
// 332.711 us; speedup vs baseline: 1.3399x; 1.0207x over previous
//
#include <hip/hip_runtime.h>
#include <hip/hip_bf16.h>
#include <math.h>

#define B_ 16
#define C_ 512
#define N_ 4096
#define NCOL (B_ * N_)  // 65536 columns (b, hw)

typedef short bf16x8 __attribute__((ext_vector_type(8)));
typedef ushort ushort8_t __attribute__((ext_vector_type(8)));
typedef float f32x4 __attribute__((ext_vector_type(4)));

__device__ __forceinline__ ushort f2bf(float f) {
    unsigned u = __float_as_uint(f);
    unsigned r = (u + 0x7FFFu + ((u >> 16) & 1u)) >> 16;
    return (ushort)r;
}
__device__ __forceinline__ float bf2f(ushort u) {
    return __uint_as_float((unsigned)u << 16);
}
__device__ __forceinline__ void gload_lds16(const void* g, void* l) {
    __builtin_amdgcn_global_load_lds(
        (const __attribute__((address_space(1))) unsigned int*)g,
        (__attribute__((address_space(3))) unsigned int*)l, 16, 0, 0);
}

// ---------------------------------------------------------------------------
// weight prep: Wb[i] = bf16(W[i] * g[c])  (g optional, c = flat%512)
// ---------------------------------------------------------------------------
__global__ __launch_bounds__(256) void wprep_k(const float* __restrict__ W,
                                               const float* __restrict__ g,
                                               ushort* __restrict__ Wb, int nvec)
{
    int i = blockIdx.x * 256 + threadIdx.x;
    if (i >= nvec) return;
    float4 wv = reinterpret_cast<const float4*>(W)[i];
    if (g) {
        const float4 gv = *reinterpret_cast<const float4*>(g + ((i * 4) & 511));
        wv.x *= gv.x; wv.y *= gv.y; wv.z *= gv.z; wv.w *= gv.w;
    }
    ushort4 u;
    u.x = f2bf(wv.x); u.y = f2bf(wv.y); u.z = f2bf(wv.z); u.w = f2bf(wv.w);
    reinterpret_cast<ushort4*>(Wb)[i] = u;
}

// ---------------------------------------------------------------------------
// transpose+convert+colnorm-partial:
//   Xt[b][n][c] = bf16(x[b][c][n]);  csq1[ctile][b*4096+n] += sum_c x^2
// ---------------------------------------------------------------------------
__global__ __launch_bounds__(256) void transpose_k(const float* __restrict__ X,
                                                   ushort* __restrict__ Xt,
                                                   float* __restrict__ csq1)
{
    __shared__ float t[64][65];
    __shared__ float sq[4][64];
    const int b = blockIdx.z, n0 = blockIdx.x * 64, c0 = blockIdx.y * 64;
    const int tid = threadIdx.x;
    const int tx = tid & 63, ty = tid >> 6;
    const float* xp = X + ((size_t)b * C_ + c0) * N_ + n0;
    float local = 0.f;
    #pragma unroll
    for (int i = 0; i < 16; ++i) {
        float v = xp[(size_t)(ty + 4 * i) * N_ + tx];
        t[ty + 4 * i][tx] = v;
        local += v * v;
    }
    sq[ty][tx] = local;
    __syncthreads();
    #pragma unroll
    for (int i = 0; i < 4; ++i) {
        int nl = (tid >> 4) + i * 16;
        int cl = (tid & 15) * 4;
        ushort4 u;
        u.x = f2bf(t[cl + 0][nl]);
        u.y = f2bf(t[cl + 1][nl]);
        u.z = f2bf(t[cl + 2][nl]);
        u.w = f2bf(t[cl + 3][nl]);
        *reinterpret_cast<ushort4*>(Xt + ((size_t)b * N_ + n0 + nl) * 512 + c0 + cl) = u;
    }
    if (tid < 64)
        csq1[(size_t)blockIdx.y * NCOL + (size_t)b * N_ + n0 + tid] =
            sq[0][tid] + sq[1][tid] + sq[2][tid] + sq[3][tid];
}

// ---------------------------------------------------------------------------
// reduce 8 csq1 partials -> rs1 = sqrt(512)/max(||x_col||, eps)
// ---------------------------------------------------------------------------
__global__ __launch_bounds__(256) void rs1_reduce_k(const float* __restrict__ csq1,
                                                    float* __restrict__ rs1)
{
    int col = blockIdx.x * 256 + threadIdx.x;
    float s = 0.f;
    #pragma unroll
    for (int j = 0; j < 8; ++j) s += csq1[(size_t)j * NCOL + col];
    rs1[col] = 22.627416998f / fmaxf(sqrtf(s), 1e-12f);
}

// ---------------------------------------------------------------------------
// MFMA GEMM1 (256x256 tile, 8 waves 2x4, BK=64, double-buffered LDS,
// per-phase interleave + counted vmcnt):  acc[o][n] = sum_c A[o][c]*Bt[b][n][c]
// Epilogue: acc *= rs1[b][n];
//   part 0 (q): softmax over d * 0.125 -> qT[bh][n][64] bf16 (8B packed stores)
//   part 1/2 (k/v): -> bf16 raw [bh*64+d][n]
// ---------------------------------------------------------------------------
__global__ __launch_bounds__(512, 2)
void mfma_gemm(const ushort* __restrict__ A, const ushort* __restrict__ Bt,
               const float* __restrict__ rs1,
               ushort* __restrict__ qT, ushort* __restrict__ kd,
               ushort* __restrict__ vd)
{
    // lds[buf][A/B][256 rows][8 chunks][16B]
    __shared__ __align__(16) char lds[2][2][32768];
    const int b  = blockIdx.z;
    const int n0 = blockIdx.x * 256;
    const int m0 = blockIdx.y * 256;
    const int tid = threadIdx.x;
    const int w = tid >> 6, l = tid & 63;
    const int wm = w >> 2, wn = w & 3;          // 2 x 4 waves
    const int lq = l >> 4, lr = l & 15;
    const ushort* Bb = Bt + (size_t)b * N_ * 512;

    f32x4 acc[8][4];
    #pragma unroll
    for (int i = 0; i < 8; ++i)
        #pragma unroll
        for (int j = 0; j < 4; ++j)
            #pragma unroll
            for (int r = 0; r < 4; ++r) acc[i][j][r] = 0.f;

#define STAGE_STEP(t, i)                                                      \
    do {                                                                      \
        const int kb_ = (t) * 128;                                            \
        const int idx_ = (i) * 512 + tid;                                     \
        const int r_ = idx_ >> 3;                                             \
        const int ch_ = (idx_ & 7) ^ (r_ & 7);                                \
        gload_lds16((const char*)A + (size_t)(m0 + r_) * 1024 + kb_ + ch_ * 16,\
                    &lds[(t) & 1][0][idx_ * 16]);                             \
        gload_lds16((const char*)Bb + (size_t)(n0 + r_) * 1024 + kb_ + ch_ * 16,\
                    &lds[(t) & 1][1][idx_ * 16]);                             \
    } while (0)

    #pragma unroll
    for (int i = 0; i < 4; ++i) STAGE_STEP(0, i);

    bf16x8 bfr[4];
    #pragma unroll 2
    for (int t = 0; t < 8; ++t) {
        const char* As = lds[t & 1][0];
        const char* Bs = lds[t & 1][1];
        #pragma unroll
        for (int ph = 0; ph < 4; ++ph) {
            const int kk = ph >> 1, mg = ph & 1;
            bf16x8 af[4];
            if (ph != 0) {
                #pragma unroll
                for (int m2 = 0; m2 < 4; ++m2) {
                    int ra = wm * 128 + (mg * 4 + m2) * 16 + lr;
                    int ch = (kk * 4 + lq) ^ (ra & 7);
                    af[m2] = *(const bf16x8*)(As + ra * 128 + ch * 16);
                }
                if (mg == 0) {
                    #pragma unroll
                    for (int nf = 0; nf < 4; ++nf) {
                        int rb = wn * 64 + nf * 16 + lr;
                        int ch = (kk * 4 + lq) ^ (rb & 7);
                        bfr[nf] = *(const bf16x8*)(Bs + rb * 128 + ch * 16);
                    }
                }
            }
            if (t < 7) STAGE_STEP(t + 1, ph);
            if (ph == 0) {
                if (t < 7) { asm volatile("s_waitcnt vmcnt(2)" ::: "memory"); }
                else       { asm volatile("s_waitcnt vmcnt(0)" ::: "memory"); }
            }
            __builtin_amdgcn_s_barrier();
            if (ph == 0) {
                #pragma unroll
                for (int m2 = 0; m2 < 4; ++m2) {
                    int ra = wm * 128 + m2 * 16 + lr;
                    int ch = lq ^ (ra & 7);
                    af[m2] = *(const bf16x8*)(As + ra * 128 + ch * 16);
                }
                #pragma unroll
                for (int nf = 0; nf < 4; ++nf) {
                    int rb = wn * 64 + nf * 16 + lr;
                    int ch = lq ^ (rb & 7);
                    bfr[nf] = *(const bf16x8*)(Bs + rb * 128 + ch * 16);
                }
            }
            asm volatile("s_waitcnt lgkmcnt(0)" ::: "memory");
            __builtin_amdgcn_sched_barrier(0);
            __builtin_amdgcn_s_setprio(1);
            #pragma unroll
            for (int m2 = 0; m2 < 4; ++m2)
                #pragma unroll
                for (int nf = 0; nf < 4; ++nf)
                    acc[mg * 4 + m2][nf] = __builtin_amdgcn_mfma_f32_16x16x32_bf16(
                        af[m2], bfr[nf], acc[mg * 4 + m2][nf], 0, 0, 0);
            __builtin_amdgcn_s_setprio(0);
            __builtin_amdgcn_s_barrier();
        }
    }
#undef STAGE_STEP

    const int part = m0 >> 9;                       // block-uniform (0/1/2)
    const int mloc = (m0 & 511) + wm * 128;         // 0/128/256/384 within part
    const int nbase = n0 + wn * 64;
    if (part == 0) {
        // q: *rs1, softmax over the 64 d-rows of each head, *0.125,
        // write qT[bh][n][64] bf16 with packed 8B stores.
        #pragma unroll
        for (int hg = 0; hg < 2; ++hg) {
            const int head = (mloc >> 6) + hg;
            #pragma unroll
            for (int nf = 0; nf < 4; ++nf) {
                const int n = nbase + nf * 16 + lr;
                const float sc = rs1[(size_t)b * N_ + n];
                float v[4][4];
                float mx = -1e30f;
                #pragma unroll
                for (int m2 = 0; m2 < 4; ++m2)
                    #pragma unroll
                    for (int r = 0; r < 4; ++r) {
                        v[m2][r] = acc[hg * 4 + m2][nf][r] * sc;
                        mx = fmaxf(mx, v[m2][r]);
                    }
                mx = fmaxf(mx, __shfl_xor(mx, 16));
                mx = fmaxf(mx, __shfl_xor(mx, 32));
                float s = 0.f;
                #pragma unroll
                for (int m2 = 0; m2 < 4; ++m2)
                    #pragma unroll
                    for (int r = 0; r < 4; ++r) {
                        v[m2][r] = __expf(v[m2][r] - mx);
                        s += v[m2][r];
                    }
                s += __shfl_xor(s, 16);
                s += __shfl_xor(s, 32);
                const float r8 = 0.125f / s;
                ushort* qp = qT + (((size_t)b * 8 + head) * N_ + n) * 64;
                #pragma unroll
                for (int m2 = 0; m2 < 4; ++m2) {
                    ushort4 u;
                    u.x = f2bf(v[m2][0] * r8);
                    u.y = f2bf(v[m2][1] * r8);
                    u.z = f2bf(v[m2][2] * r8);
                    u.w = f2bf(v[m2][3] * r8);
                    *reinterpret_cast<ushort4*>(qp + m2 * 16 + lq * 4) = u;
                }
            }
        }
    } else {
        ushort* dst = (part == 1) ? kd : vd;
        #pragma unroll
        for (int nf = 0; nf < 4; ++nf) {
            const int n = nbase + nf * 16 + lr;
            const float sc = rs1[(size_t)b * N_ + n];
            #pragma unroll
            for (int mf = 0; mf < 8; ++mf) {
                const int o = mloc + mf * 16 + lq * 4;
                #pragma unroll
                for (int r = 0; r < 4; ++r)
                    dst[((size_t)b * 512 + o + r) * N_ + n] =
                        f2bf(acc[mf][nf][r] * sc);
            }
        }
    }
}

// ---------------------------------------------------------------------------
// row stats for k-softmax: per row (bh*64+d) of 4096 bf16 scores ->
// rowm = max, rowr = 1/sum(exp(v-max)).  One wave per row.
// ---------------------------------------------------------------------------
__global__ __launch_bounds__(256) void rowstat_k(const ushort* __restrict__ kk,
                                                 float* __restrict__ rowm,
                                                 float* __restrict__ rowr)
{
    const int row = blockIdx.x * 4 + (threadIdx.x >> 6);
    const int lane = threadIdx.x & 63;
    const ushort* p = kk + (size_t)row * N_;
    float vals[64];
    #pragma unroll
    for (int j = 0; j < 8; ++j) {
        ushort8_t u = *reinterpret_cast<const ushort8_t*>(p + lane * 8 + j * 512);
        #pragma unroll
        for (int t = 0; t < 8; ++t) vals[j * 8 + t] = bf2f(u[t]);
    }
    float mx = -1e30f;
    #pragma unroll
    for (int i = 0; i < 64; ++i) mx = fmaxf(mx, vals[i]);
    #pragma unroll
    for (int o = 32; o >= 1; o >>= 1) mx = fmaxf(mx, __shfl_xor(mx, o));
    float s = 0.f;
    #pragma unroll
    for (int i = 0; i < 64; ++i) s += __expf(vals[i] - mx);
    #pragma unroll
    for (int o = 32; o >= 1; o >>= 1) s += __shfl_xor(s, o);
    if (lane == 0) { rowm[row] = mx; rowr[row] = 1.f / s; }
}

// ---------------------------------------------------------------------------
// ctx (MFMA): ctxp[bh][chunk][e][d] = rowr[d] *
//     sum_{n in chunk} v[bh][e][n] * exp(k[bh][d][n]-rowm[d])
// ---------------------------------------------------------------------------
__global__ __launch_bounds__(256) void ctx_k(const ushort* __restrict__ kk,
                                             const ushort* __restrict__ vv,
                                             const float* __restrict__ rowm,
                                             const float* __restrict__ rowr,
                                             float* __restrict__ ctxp)
{
    const int bh = blockIdx.x, chunk = blockIdx.y;
    const ushort* kp = kk + (size_t)bh * 64 * N_;
    const ushort* vp = vv + (size_t)bh * 64 * N_;
    __shared__ __align__(16) ushort kx[64 * 128];   // 16 KiB
    __shared__ __align__(16) ushort vx[64 * 128];   // 16 KiB
    __shared__ float rm[64];
    const int tid = threadIdx.x;
    const int w = tid >> 6, l = tid & 63;
    const int lq = l >> 4, lr = l & 15;
    const int we = w >> 1, wd = w & 1;              // e-half, d-half of 64x64
    if (tid < 64) rm[tid] = rowm[(size_t)bh * 64 + tid];
    __syncthreads();

    f32x4 acc[2][2];
    #pragma unroll
    for (int i = 0; i < 2; ++i)
        #pragma unroll
        for (int j = 0; j < 2; ++j)
            #pragma unroll
            for (int r = 0; r < 4; ++r) acc[i][j][r] = 0.f;

    for (int s = 0; s < 8; ++s) {
        const int n0 = chunk * 1024 + s * 128;
        #pragma unroll
        for (int i = 0; i < 4; ++i) {
            int idx = i * 256 + tid;
            int row = idx >> 4;
            int ch  = (idx & 15) ^ (row & 15);
            gload_lds16((const char*)(vp + (size_t)row * N_ + n0 + ch * 8),
                        (char*)vx + idx * 16);
        }
        #pragma unroll
        for (int i = 0; i < 4; ++i) {
            int idx = i * 256 + tid;
            int row = idx >> 4;
            int ch  = idx & 15;
            ushort8_t u = *reinterpret_cast<const ushort8_t*>(
                kp + (size_t)row * N_ + n0 + ch * 8);
            float m_ = rm[row];
            ushort8_t o;
            #pragma unroll
            for (int t = 0; t < 8; ++t) o[t] = f2bf(__expf(bf2f(u[t]) - m_));
            *(ushort8_t*)((char*)kx + (row * 16 + (ch ^ (row & 15))) * 16) = o;
        }
        __syncthreads();
        #pragma unroll
        for (int k2 = 0; k2 < 4; ++k2) {
            bf16x8 af[2], bfr[2];
            #pragma unroll
            for (int i = 0; i < 2; ++i) {
                int re = we * 32 + i * 16 + lr;
                int cha = (k2 * 4 + lq) ^ (re & 15);
                af[i] = *(const bf16x8*)((const char*)vx + (re * 16 + cha) * 16);
                int rd = wd * 32 + i * 16 + lr;
                int chb = (k2 * 4 + lq) ^ (rd & 15);
                bfr[i] = *(const bf16x8*)((const char*)kx + (rd * 16 + chb) * 16);
            }
            #pragma unroll
            for (int i = 0; i < 2; ++i)
                #pragma unroll
                for (int j = 0; j < 2; ++j)
                    acc[i][j] = __builtin_amdgcn_mfma_f32_16x16x32_bf16(
                        af[i], bfr[j], acc[i][j], 0, 0, 0);
        }
        __syncthreads();
    }
    float* cbase = ctxp + ((size_t)bh * 4 + chunk) * 4096;
    #pragma unroll
    for (int j = 0; j < 2; ++j) {
        const int d = wd * 32 + j * 16 + lr;
        const float rr = rowr[(size_t)bh * 64 + d];
        #pragma unroll
        for (int i = 0; i < 2; ++i) {
            const int e = we * 32 + i * 16 + lq * 4;
            #pragma unroll
            for (int r = 0; r < 4; ++r)
                cbase[(size_t)(e + r) * 64 + d] = acc[i][j][r] * rr;
        }
    }
}

// ---------------------------------------------------------------------------
// ctxsum: ctxb[bh][e][d] = bf16( sum_chunk ctxp[bh][chunk][e][d] )
// ---------------------------------------------------------------------------
__global__ __launch_bounds__(256) void ctxsum_k(const float* __restrict__ ctxp,
                                                ushort* __restrict__ ctxb)
{
    int i4 = blockIdx.x * 256 + threadIdx.x;   // 131072 float4-groups
    int bh = i4 >> 10;
    int off = (i4 & 1023) * 4;
    const float* cp = ctxp + (size_t)bh * 16384 + off;
    float4 a0 = *(const float4*)cp;
    float4 a1 = *(const float4*)(cp + 4096);
    float4 a2 = *(const float4*)(cp + 8192);
    float4 a3 = *(const float4*)(cp + 12288);
    ushort4 u;
    u.x = f2bf(a0.x + a1.x + a2.x + a3.x);
    u.y = f2bf(a0.y + a1.y + a2.y + a3.y);
    u.z = f2bf(a0.z + a1.z + a2.z + a3.z);
    u.w = f2bf(a0.w + a1.w + a2.w + a3.w);
    *reinterpret_cast<ushort4*>(ctxb + (size_t)bh * 4096 + off) = u;
}

// ---------------------------------------------------------------------------
// GEMM2 fused (attn + output GEMM + bias + rms-norm):
// per block (n-tile 64, b): phase A builds at2-tile[64 n][512 c] in LDS from
// qT & ctxb (one head per wave, MFMA); main loop: out[o][n] = Wout @ at2-tile,
// full M=512 per block; epilogue: in-block column rms-norm * g2 -> final f32.
// ---------------------------------------------------------------------------
__global__ __launch_bounds__(512, 1)
void gemm2f_k(const ushort* __restrict__ A,      // Woutb [512][512] bf16
              const ushort* __restrict__ qT,     // [bh][n][64] bf16
              const ushort* __restrict__ ctxb,   // [bh][e][d] bf16
              const float* __restrict__ bias,
              const float* __restrict__ g2,
              float* __restrict__ outp)
{
    __shared__ __align__(16) char As[65536];   // phase A: qT[8h][64n][8ch]; main: Wout tile [512m][8ch]
    __shared__ __align__(16) char Bs[65536];   // phase A: ctx[8h][64e][8ch] -> at2-tile [64n][512c] swz
    const int b  = blockIdx.y;
    const int n0 = blockIdx.x * 64;
    const int tid = threadIdx.x;
    const int w = tid >> 6, l = tid & 63;
    const int lq = l >> 4, lr = l & 15;

    // ---- phase A: stage qT (8 heads) and ctx (8 heads)
    {
        const int n = tid >> 3;
        const int j = tid & 7;
        const int ch = j ^ (n & 7);
        #pragma unroll
        for (int h = 0; h < 8; ++h) {
            gload_lds16(qT + (((size_t)b * 8 + h) * N_ + n0 + n) * 64 + ch * 8,
                        As + h * 8192 + tid * 16);
            gload_lds16(ctxb + (((size_t)b * 8 + h) * 64 + n) * 64 + ch * 8,
                        Bs + h * 8192 + tid * 16);
        }
    }
    __syncthreads();

    // frags: wave w handles head w.  A = qT rows (n), B = ctx rows (e), K = d.
    bf16x8 paf[4][2], pbf[4][2];
    #pragma unroll
    for (int mf = 0; mf < 4; ++mf)
        #pragma unroll
        for (int k2 = 0; k2 < 2; ++k2) {
            int rr = mf * 16 + lr;
            int sl = (k2 * 4 + lq) ^ (rr & 7);
            paf[mf][k2] = *(const bf16x8*)(As + w * 8192 + rr * 128 + sl * 16);
            pbf[mf][k2] = *(const bf16x8*)(Bs + w * 8192 + rr * 128 + sl * 16);
        }
    __syncthreads();   // all reads done before Bs is overwritten

    f32x4 pacc[4][4];
    #pragma unroll
    for (int i = 0; i < 4; ++i)
        #pragma unroll
        for (int j = 0; j < 4; ++j)
            #pragma unroll
            for (int r = 0; r < 4; ++r) pacc[i][j][r] = 0.f;
    #pragma unroll
    for (int k2 = 0; k2 < 2; ++k2)
        #pragma unroll
        for (int mf = 0; mf < 4; ++mf)
            #pragma unroll
            for (int nf = 0; nf < 4; ++nf)
                pacc[mf][nf] = __builtin_amdgcn_mfma_f32_16x16x32_bf16(
                    paf[mf][k2], pbf[nf][k2], pacc[mf][nf], 0, 0, 0);

    // write at2-tile to Bs: [n][c], byte = (n*1024 + c*2) ^ ((n&7)<<4)
    #pragma unroll
    for (int mf = 0; mf < 4; ++mf)
        #pragma unroll
        for (int nf = 0; nf < 4; ++nf)
            #pragma unroll
            for (int r = 0; r < 4; ++r) {
                int n = mf * 16 + lq * 4 + r;
                int c = w * 64 + nf * 16 + lr;
                *(ushort*)(Bs + ((n * 1024 + c * 2) ^ ((n & 7) << 4))) =
                    f2bf(pacc[mf][nf][r]);
            }
    __syncthreads();

    // ---- main loop: out[m][n] = sum_c Wout[m][c] * at2[n][c], 8 K-steps
    f32x4 acc[4][4];
    #pragma unroll
    for (int i = 0; i < 4; ++i)
        #pragma unroll
        for (int j = 0; j < 4; ++j)
            #pragma unroll
            for (int r = 0; r < 4; ++r) acc[i][j][r] = 0.f;

    for (int t = 0; t < 8; ++t) {
        #pragma unroll
        for (int jj = 0; jj < 8; ++jj) {
            int idx = jj * 512 + tid;
            int m = idx >> 3;
            int ch = (idx & 7) ^ (m & 7);
            gload_lds16((const char*)A + (size_t)m * 1024 + t * 128 + ch * 16,
                        As + idx * 16);
        }
        __syncthreads();
        #pragma unroll
        for (int kk = 0; kk < 2; ++kk) {
            bf16x8 af[4], bfv[4];
            #pragma unroll
            for (int mf = 0; mf < 4; ++mf) {
                int m = w * 64 + mf * 16 + lr;
                int sl = (kk * 4 + lq) ^ (m & 7);
                af[mf] = *(const bf16x8*)(As + m * 128 + sl * 16);
            }
            #pragma unroll
            for (int nf = 0; nf < 4; ++nf) {
                int n = nf * 16 + lr;
                int sl = (kk * 4 + lq) ^ (n & 7);
                bfv[nf] = *(const bf16x8*)(Bs + n * 1024 + t * 128 + sl * 16);
            }
            #pragma unroll
            for (int mf = 0; mf < 4; ++mf)
                #pragma unroll
                for (int nf = 0; nf < 4; ++nf)
                    acc[mf][nf] = __builtin_amdgcn_mfma_f32_16x16x32_bf16(
                        af[mf], bfv[nf], acc[mf][nf], 0, 0, 0);
        }
        __syncthreads();
    }

    // ---- epilogue: bias, column sumsq, rms-norm, final write
    float4 bv[4], gv[4];
    #pragma unroll
    for (int mf = 0; mf < 4; ++mf) {
        bv[mf] = *reinterpret_cast<const float4*>(bias + w * 64 + mf * 16 + lq * 4);
        gv[mf] = *reinterpret_cast<const float4*>(g2   + w * 64 + mf * 16 + lq * 4);
    }
    float csq[4] = {};
    #pragma unroll
    for (int mf = 0; mf < 4; ++mf)
        #pragma unroll
        for (int nf = 0; nf < 4; ++nf)
            #pragma unroll
            for (int r = 0; r < 4; ++r) {
                float wv = acc[mf][nf][r] + ((const float*)&bv[mf])[r];
                acc[mf][nf][r] = wv;
                csq[nf] += wv * wv;
            }
    #pragma unroll
    for (int nf = 0; nf < 4; ++nf) {
        csq[nf] += __shfl_xor(csq[nf], 16);
        csq[nf] += __shfl_xor(csq[nf], 32);
    }
    float* red  = (float*)As;       // 8 x 64 floats
    float* rs2s = red + 512;        // 64 floats
    if (lq == 0) {
        #pragma unroll
        for (int nf = 0; nf < 4; ++nf)
            red[w * 64 + nf * 16 + lr] = csq[nf];
    }
    __syncthreads();
    if (tid < 64) {
        float s = 0.f;
        #pragma unroll
        for (int j = 0; j < 8; ++j) s += red[j * 64 + tid];
        rs2s[tid] = 22.627416998f / fmaxf(sqrtf(s), 1e-12f);
    }
    __syncthreads();
    #pragma unroll
    for (int nf = 0; nf < 4; ++nf) {
        const float rsv = rs2s[nf * 16 + lr];
        const int n = n0 + nf * 16 + lr;
        #pragma unroll
        for (int mf = 0; mf < 4; ++mf) {
            const int o = w * 64 + mf * 16 + lq * 4;
            float* p = outp + ((size_t)b * 512 + o) * N_ + n;
            #pragma unroll
            for (int r = 0; r < 4; ++r)
                p[(size_t)r * N_] = acc[mf][nf][r] * rsv * ((const float*)&gv[mf])[r];
        }
    }
}

// ---------------------------------------------------------------------------
extern "C" void kernel_launch(void* const* d_in, const int* in_sizes, int n_in,
                              void* d_out, int out_size, void* d_ws, size_t ws_size,
                              hipStream_t stream)
{
    const float* x    = (const float*)d_in[0];
    const float* g1   = (const float*)d_in[1];
    const float* Wqkv = (const float*)d_in[2];
    const float* Wout = (const float*)d_in[3];
    const float* bout = (const float*)d_in[4];
    const float* g2   = (const float*)d_in[5];
    float* out = (float*)d_out;

    // ws layout (<= 258.25 MiB):
    //   [0,64Mi)     qT bf16 [bh][n][64]  (csq1 f32 2Mi aliased pre-GEMM1)
    //   [64,128Mi)   kbuf bf16
    //   [128,192Mi)  vbuf bf16
    //   [192,256Mi)  Xt bf16              -> after GEMM1: ctxp f32 (8Mi) @192,
    //                                       rowm/rowr @200Mi, ctxb bf16 @201Mi
    //   [256Mi..)    Wqkvb(1.5Mi) Woutb(0.5Mi) rs1(256Ki)
    char* wsb = (char*)d_ws;
    ushort* qbuf  = (ushort*)wsb;
    float*  csq1  = (float*)wsb;     // alias (dead once rs1 computed)
    ushort* kbuf  = (ushort*)(wsb + ((size_t)64 << 20));
    ushort* vbuf  = (ushort*)(wsb + ((size_t)128 << 20));
    ushort* Xt    = (ushort*)(wsb + ((size_t)192 << 20));
    float*  ctxp  = (float*)Xt;
    float*  rowm  = (float*)(wsb + ((size_t)200 << 20));
    float*  rowr  = rowm + 8192;
    ushort* ctxb  = (ushort*)(wsb + ((size_t)201 << 20));
    char*   tail  = wsb + ((size_t)256 << 20);
    ushort* Wqkvb = (ushort*)tail;
    ushort* Woutb = (ushort*)(tail + (size_t)1536 * 512 * 2);
    float*  rs1   = (float*)(tail + (size_t)1536 * 512 * 2 + (size_t)512 * 512 * 2);

    // 1. weight prep (bf16; g1 folded into Wqkv)
    wprep_k<<<768, 256, 0, stream>>>(Wqkv, g1, Wqkvb, 1536 * 512 / 4);
    wprep_k<<<256, 256, 0, stream>>>(Wout, nullptr, Woutb, 512 * 512 / 4);
    // 2. Xt[b][n][c] = bf16(x^T) + column sumsq partials
    transpose_k<<<dim3(64, 8, 16), 256, 0, stream>>>(x, Xt, csq1);
    // 3. rs1 = sqrt(512)/||x_col||
    rs1_reduce_k<<<256, 256, 0, stream>>>(csq1, rs1);
    // 4. QKV GEMM: qT (softmaxed, transposed), k, v (bf16)
    mfma_gemm<<<dim3(16, 6, B_), 512, 0, stream>>>(Wqkvb, Xt, rs1,
                                                   qbuf, kbuf, vbuf);
    // 5. k row stats (max, 1/sum-exp)
    rowstat_k<<<2048, 256, 0, stream>>>(kbuf, rowm, rowr);
    // 6. context partials (MFMA, softmax applied on the fly) -> ctxp[e][d]
    ctx_k<<<dim3(B_ * 8, 4), 256, 0, stream>>>(kbuf, vbuf, rowm, rowr, ctxp);
    // 7. sum partials -> ctxb bf16
    ctxsum_k<<<512, 256, 0, stream>>>(ctxp, ctxb);
    // 8. fused attn + output GEMM + bias + rms-norm -> d_out f32 (final)
    gemm2f_k<<<dim3(64, B_), 512, 0, stream>>>(Woutb, qbuf, ctxb, bout, g2, out);
}

// Round 9
// 300.781 us; speedup vs baseline: 1.4822x; 1.1062x over previous
//
#include <hip/hip_runtime.h>
#include <hip/hip_bf16.h>
#include <math.h>

#define B_ 16
#define C_ 512
#define N_ 4096
#define NCOL (B_ * N_)  // 65536 columns (b, hw)

typedef short bf16x8 __attribute__((ext_vector_type(8)));
typedef ushort ushort8_t __attribute__((ext_vector_type(8)));
typedef float f32x4 __attribute__((ext_vector_type(4)));

__device__ __forceinline__ ushort f2bf(float f) {
    unsigned u = __float_as_uint(f);
    unsigned r = (u + 0x7FFFu + ((u >> 16) & 1u)) >> 16;
    return (ushort)r;
}
__device__ __forceinline__ float bf2f(ushort u) {
    return __uint_as_float((unsigned)u << 16);
}
__device__ __forceinline__ void gload_lds16(const void* g, void* l) {
    __builtin_amdgcn_global_load_lds(
        (const __attribute__((address_space(1))) unsigned int*)g,
        (__attribute__((address_space(3))) unsigned int*)l, 16, 0, 0);
}

// ---------------------------------------------------------------------------
// weight prep: Wb[i] = bf16(W[i] * g[c])  (g optional, c = flat%512)
// ---------------------------------------------------------------------------
__global__ __launch_bounds__(256) void wprep_k(const float* __restrict__ W,
                                               const float* __restrict__ g,
                                               ushort* __restrict__ Wb, int nvec)
{
    int i = blockIdx.x * 256 + threadIdx.x;
    if (i >= nvec) return;
    float4 wv = reinterpret_cast<const float4*>(W)[i];
    if (g) {
        const float4 gv = *reinterpret_cast<const float4*>(g + ((i * 4) & 511));
        wv.x *= gv.x; wv.y *= gv.y; wv.z *= gv.z; wv.w *= gv.w;
    }
    ushort4 u;
    u.x = f2bf(wv.x); u.y = f2bf(wv.y); u.z = f2bf(wv.z); u.w = f2bf(wv.w);
    reinterpret_cast<ushort4*>(Wb)[i] = u;
}

// ---------------------------------------------------------------------------
// transpose+convert+colnorm-partial:
//   Xt[b][n][c] = bf16(x[b][c][n]);  csq1[ctile][b*4096+n] += sum_c x^2
// ---------------------------------------------------------------------------
__global__ __launch_bounds__(256) void transpose_k(const float* __restrict__ X,
                                                   ushort* __restrict__ Xt,
                                                   float* __restrict__ csq1)
{
    __shared__ float t[64][65];
    __shared__ float sq[4][64];
    const int b = blockIdx.z, n0 = blockIdx.x * 64, c0 = blockIdx.y * 64;
    const int tid = threadIdx.x;
    const int tx = tid & 63, ty = tid >> 6;
    const float* xp = X + ((size_t)b * C_ + c0) * N_ + n0;
    float local = 0.f;
    #pragma unroll
    for (int i = 0; i < 16; ++i) {
        float v = xp[(size_t)(ty + 4 * i) * N_ + tx];
        t[ty + 4 * i][tx] = v;
        local += v * v;
    }
    sq[ty][tx] = local;
    __syncthreads();
    #pragma unroll
    for (int i = 0; i < 4; ++i) {
        int nl = (tid >> 4) + i * 16;
        int cl = (tid & 15) * 4;
        ushort4 u;
        u.x = f2bf(t[cl + 0][nl]);
        u.y = f2bf(t[cl + 1][nl]);
        u.z = f2bf(t[cl + 2][nl]);
        u.w = f2bf(t[cl + 3][nl]);
        *reinterpret_cast<ushort4*>(Xt + ((size_t)b * N_ + n0 + nl) * 512 + c0 + cl) = u;
    }
    if (tid < 64)
        csq1[(size_t)blockIdx.y * NCOL + (size_t)b * N_ + n0 + tid] =
            sq[0][tid] + sq[1][tid] + sq[2][tid] + sq[3][tid];
}

// ---------------------------------------------------------------------------
// reduce 8 csq1 partials -> rs1 = sqrt(512)/max(||x_col||, eps)
// ---------------------------------------------------------------------------
__global__ __launch_bounds__(256) void rs1_reduce_k(const float* __restrict__ csq1,
                                                    float* __restrict__ rs1)
{
    int col = blockIdx.x * 256 + threadIdx.x;
    float s = 0.f;
    #pragma unroll
    for (int j = 0; j < 8; ++j) s += csq1[(size_t)j * NCOL + col];
    rs1[col] = 22.627416998f / fmaxf(sqrtf(s), 1e-12f);
}

// ---------------------------------------------------------------------------
// MFMA GEMM1 (256x256 tile, 8 waves 2x4, BK=64, double-buffered LDS,
// per-phase interleave + counted vmcnt):  acc[o][n] = sum_c A[o][c]*Bt[b][n][c]
// Epilogue: acc *= rs1[b][n];
//   part 0 (q): softmax over d * 0.125 -> qT2[b][n][h*64+d] bf16 (8B stores)
//   part 1/2 (k/v): -> bf16 raw [bh*64+d][n]
// ---------------------------------------------------------------------------
__global__ __launch_bounds__(512, 2)
void mfma_gemm(const ushort* __restrict__ A, const ushort* __restrict__ Bt,
               const float* __restrict__ rs1,
               ushort* __restrict__ qT2, ushort* __restrict__ kd,
               ushort* __restrict__ vd)
{
    // lds[buf][A/B][256 rows][8 chunks][16B]
    __shared__ __align__(16) char lds[2][2][32768];
    const int b  = blockIdx.z;
    const int n0 = blockIdx.x * 256;
    const int m0 = blockIdx.y * 256;
    const int tid = threadIdx.x;
    const int w = tid >> 6, l = tid & 63;
    const int wm = w >> 2, wn = w & 3;          // 2 x 4 waves
    const int lq = l >> 4, lr = l & 15;
    const ushort* Bb = Bt + (size_t)b * N_ * 512;

    f32x4 acc[8][4];
    #pragma unroll
    for (int i = 0; i < 8; ++i)
        #pragma unroll
        for (int j = 0; j < 4; ++j)
            #pragma unroll
            for (int r = 0; r < 4; ++r) acc[i][j][r] = 0.f;

#define STAGE_STEP(t, i)                                                      \
    do {                                                                      \
        const int kb_ = (t) * 128;                                            \
        const int idx_ = (i) * 512 + tid;                                     \
        const int r_ = idx_ >> 3;                                             \
        const int ch_ = (idx_ & 7) ^ (r_ & 7);                                \
        gload_lds16((const char*)A + (size_t)(m0 + r_) * 1024 + kb_ + ch_ * 16,\
                    &lds[(t) & 1][0][idx_ * 16]);                             \
        gload_lds16((const char*)Bb + (size_t)(n0 + r_) * 1024 + kb_ + ch_ * 16,\
                    &lds[(t) & 1][1][idx_ * 16]);                             \
    } while (0)

    #pragma unroll
    for (int i = 0; i < 4; ++i) STAGE_STEP(0, i);

    bf16x8 bfr[4];
    #pragma unroll 2
    for (int t = 0; t < 8; ++t) {
        const char* As = lds[t & 1][0];
        const char* Bs = lds[t & 1][1];
        #pragma unroll
        for (int ph = 0; ph < 4; ++ph) {
            const int kk = ph >> 1, mg = ph & 1;
            bf16x8 af[4];
            if (ph != 0) {
                #pragma unroll
                for (int m2 = 0; m2 < 4; ++m2) {
                    int ra = wm * 128 + (mg * 4 + m2) * 16 + lr;
                    int ch = (kk * 4 + lq) ^ (ra & 7);
                    af[m2] = *(const bf16x8*)(As + ra * 128 + ch * 16);
                }
                if (mg == 0) {
                    #pragma unroll
                    for (int nf = 0; nf < 4; ++nf) {
                        int rb = wn * 64 + nf * 16 + lr;
                        int ch = (kk * 4 + lq) ^ (rb & 7);
                        bfr[nf] = *(const bf16x8*)(Bs + rb * 128 + ch * 16);
                    }
                }
            }
            if (t < 7) STAGE_STEP(t + 1, ph);
            if (ph == 0) {
                if (t < 7) { asm volatile("s_waitcnt vmcnt(2)" ::: "memory"); }
                else       { asm volatile("s_waitcnt vmcnt(0)" ::: "memory"); }
            }
            __builtin_amdgcn_s_barrier();
            if (ph == 0) {
                #pragma unroll
                for (int m2 = 0; m2 < 4; ++m2) {
                    int ra = wm * 128 + m2 * 16 + lr;
                    int ch = lq ^ (ra & 7);
                    af[m2] = *(const bf16x8*)(As + ra * 128 + ch * 16);
                }
                #pragma unroll
                for (int nf = 0; nf < 4; ++nf) {
                    int rb = wn * 64 + nf * 16 + lr;
                    int ch = lq ^ (rb & 7);
                    bfr[nf] = *(const bf16x8*)(Bs + rb * 128 + ch * 16);
                }
            }
            asm volatile("s_waitcnt lgkmcnt(0)" ::: "memory");
            __builtin_amdgcn_sched_barrier(0);
            __builtin_amdgcn_s_setprio(1);
            #pragma unroll
            for (int m2 = 0; m2 < 4; ++m2)
                #pragma unroll
                for (int nf = 0; nf < 4; ++nf)
                    acc[mg * 4 + m2][nf] = __builtin_amdgcn_mfma_f32_16x16x32_bf16(
                        af[m2], bfr[nf], acc[mg * 4 + m2][nf], 0, 0, 0);
            __builtin_amdgcn_s_setprio(0);
            __builtin_amdgcn_s_barrier();
        }
    }
#undef STAGE_STEP

    const int part = m0 >> 9;                       // block-uniform (0/1/2)
    const int mloc = (m0 & 511) + wm * 128;         // 0/128/256/384 within part
    const int nbase = n0 + wn * 64;
    if (part == 0) {
        // q: *rs1, softmax over the 64 d-rows of each head, *0.125,
        // write qT2[b][n][h*64+d] bf16 with packed 8B stores.
        #pragma unroll
        for (int hg = 0; hg < 2; ++hg) {
            const int head = (mloc >> 6) + hg;
            #pragma unroll
            for (int nf = 0; nf < 4; ++nf) {
                const int n = nbase + nf * 16 + lr;
                const float sc = rs1[(size_t)b * N_ + n];
                float v[4][4];
                float mx = -1e30f;
                #pragma unroll
                for (int m2 = 0; m2 < 4; ++m2)
                    #pragma unroll
                    for (int r = 0; r < 4; ++r) {
                        v[m2][r] = acc[hg * 4 + m2][nf][r] * sc;
                        mx = fmaxf(mx, v[m2][r]);
                    }
                mx = fmaxf(mx, __shfl_xor(mx, 16));
                mx = fmaxf(mx, __shfl_xor(mx, 32));
                float s = 0.f;
                #pragma unroll
                for (int m2 = 0; m2 < 4; ++m2)
                    #pragma unroll
                    for (int r = 0; r < 4; ++r) {
                        v[m2][r] = __expf(v[m2][r] - mx);
                        s += v[m2][r];
                    }
                s += __shfl_xor(s, 16);
                s += __shfl_xor(s, 32);
                const float r8 = 0.125f / s;
                ushort* qp = qT2 + ((size_t)b * N_ + n) * 512 + head * 64;
                #pragma unroll
                for (int m2 = 0; m2 < 4; ++m2) {
                    ushort4 u;
                    u.x = f2bf(v[m2][0] * r8);
                    u.y = f2bf(v[m2][1] * r8);
                    u.z = f2bf(v[m2][2] * r8);
                    u.w = f2bf(v[m2][3] * r8);
                    *reinterpret_cast<ushort4*>(qp + m2 * 16 + lq * 4) = u;
                }
            }
        }
    } else {
        ushort* dst = (part == 1) ? kd : vd;
        #pragma unroll
        for (int nf = 0; nf < 4; ++nf) {
            const int n = nbase + nf * 16 + lr;
            const float sc = rs1[(size_t)b * N_ + n];
            #pragma unroll
            for (int mf = 0; mf < 8; ++mf) {
                const int o = mloc + mf * 16 + lq * 4;
                #pragma unroll
                for (int r = 0; r < 4; ++r)
                    dst[((size_t)b * 512 + o + r) * N_ + n] =
                        f2bf(acc[mf][nf][r] * sc);
            }
        }
    }
}

// ---------------------------------------------------------------------------
// row stats for k-softmax: per row (bh*64+d) of 4096 bf16 scores ->
// rowm = max, rowr = 1/sum(exp(v-max)).  One wave per row.
// ---------------------------------------------------------------------------
__global__ __launch_bounds__(256) void rowstat_k(const ushort* __restrict__ kk,
                                                 float* __restrict__ rowm,
                                                 float* __restrict__ rowr)
{
    const int row = blockIdx.x * 4 + (threadIdx.x >> 6);
    const int lane = threadIdx.x & 63;
    const ushort* p = kk + (size_t)row * N_;
    float vals[64];
    #pragma unroll
    for (int j = 0; j < 8; ++j) {
        ushort8_t u = *reinterpret_cast<const ushort8_t*>(p + lane * 8 + j * 512);
        #pragma unroll
        for (int t = 0; t < 8; ++t) vals[j * 8 + t] = bf2f(u[t]);
    }
    float mx = -1e30f;
    #pragma unroll
    for (int i = 0; i < 64; ++i) mx = fmaxf(mx, vals[i]);
    #pragma unroll
    for (int o = 32; o >= 1; o >>= 1) mx = fmaxf(mx, __shfl_xor(mx, o));
    float s = 0.f;
    #pragma unroll
    for (int i = 0; i < 64; ++i) s += __expf(vals[i] - mx);
    #pragma unroll
    for (int o = 32; o >= 1; o >>= 1) s += __shfl_xor(s, o);
    if (lane == 0) { rowm[row] = mx; rowr[row] = 1.f / s; }
}

// ---------------------------------------------------------------------------
// ctx (MFMA): ctxp[bh][chunk][d][e] = rowr[d] *
//     sum_{n in chunk} exp(k[bh][d][n]-rowm[d]) * v[bh][e][n]
// (reference orientation: ctx[d][e]).  float4 packed stores.
// ---------------------------------------------------------------------------
__global__ __launch_bounds__(256) void ctx_k(const ushort* __restrict__ kk,
                                             const ushort* __restrict__ vv,
                                             const float* __restrict__ rowm,
                                             const float* __restrict__ rowr,
                                             float* __restrict__ ctxp)
{
    const int bh = blockIdx.x, chunk = blockIdx.y;
    const ushort* kp = kk + (size_t)bh * 64 * N_;
    const ushort* vp = vv + (size_t)bh * 64 * N_;
    __shared__ __align__(16) ushort kx[64 * 128];   // 16 KiB
    __shared__ __align__(16) ushort vx[64 * 128];   // 16 KiB
    __shared__ float rm[64];
    const int tid = threadIdx.x;
    const int w = tid >> 6, l = tid & 63;
    const int lq = l >> 4, lr = l & 15;
    const int we = w >> 1, wd = w & 1;              // e-half, d-half of 64x64
    if (tid < 64) rm[tid] = rowm[(size_t)bh * 64 + tid];
    __syncthreads();

    f32x4 acc[2][2];
    #pragma unroll
    for (int i = 0; i < 2; ++i)
        #pragma unroll
        for (int j = 0; j < 2; ++j)
            #pragma unroll
            for (int r = 0; r < 4; ++r) acc[i][j][r] = 0.f;

    for (int s = 0; s < 8; ++s) {
        const int n0 = chunk * 1024 + s * 128;
        #pragma unroll
        for (int i = 0; i < 4; ++i) {
            int idx = i * 256 + tid;
            int row = idx >> 4;
            int ch  = (idx & 15) ^ (row & 15);
            gload_lds16((const char*)(vp + (size_t)row * N_ + n0 + ch * 8),
                        (char*)vx + idx * 16);
        }
        #pragma unroll
        for (int i = 0; i < 4; ++i) {
            int idx = i * 256 + tid;
            int row = idx >> 4;
            int ch  = idx & 15;
            ushort8_t u = *reinterpret_cast<const ushort8_t*>(
                kp + (size_t)row * N_ + n0 + ch * 8);
            float m_ = rm[row];
            ushort8_t o;
            #pragma unroll
            for (int t = 0; t < 8; ++t) o[t] = f2bf(__expf(bf2f(u[t]) - m_));
            *(ushort8_t*)((char*)kx + (row * 16 + (ch ^ (row & 15))) * 16) = o;
        }
        __syncthreads();
        #pragma unroll
        for (int k2 = 0; k2 < 4; ++k2) {
            bf16x8 af[2], bfr[2];
            #pragma unroll
            for (int i = 0; i < 2; ++i) {
                int re = we * 32 + i * 16 + lr;
                int cha = (k2 * 4 + lq) ^ (re & 15);
                af[i] = *(const bf16x8*)((const char*)vx + (re * 16 + cha) * 16);
                int rd = wd * 32 + i * 16 + lr;
                int chb = (k2 * 4 + lq) ^ (rd & 15);
                bfr[i] = *(const bf16x8*)((const char*)kx + (rd * 16 + chb) * 16);
            }
            #pragma unroll
            for (int i = 0; i < 2; ++i)
                #pragma unroll
                for (int j = 0; j < 2; ++j)
                    acc[i][j] = __builtin_amdgcn_mfma_f32_16x16x32_bf16(
                        af[i], bfr[j], acc[i][j], 0, 0, 0);
        }
        __syncthreads();
    }
    // write ctxp[bh][chunk][d][e] (e contiguous -> float4), scale by rowr[d]
    float* cbase = ctxp + ((size_t)bh * 4 + chunk) * 4096;
    #pragma unroll
    for (int j = 0; j < 2; ++j) {
        const int d = wd * 32 + j * 16 + lr;
        const float rr = rowr[(size_t)bh * 64 + d];
        #pragma unroll
        for (int i = 0; i < 2; ++i) {
            const int e0 = we * 32 + i * 16 + lq * 4;
            float4 wv;
            wv.x = acc[i][j][0] * rr;
            wv.y = acc[i][j][1] * rr;
            wv.z = acc[i][j][2] * rr;
            wv.w = acc[i][j][3] * rr;
            *reinterpret_cast<float4*>(cbase + (size_t)d * 64 + e0) = wv;
        }
    }
}

// ---------------------------------------------------------------------------
// wcbuild (MFMA): Wc[b][o][h*64+d] = bf16( sum_e Wout[o][h*64+e] *
//                                          (sum_chunk ctxp[bh][chunk][d][e]) )
// grid (2 o-halves, 8 h, 16 b), 256 threads / 4 waves; K = e = 64.
// ---------------------------------------------------------------------------
__global__ __launch_bounds__(256) void wcbuild_k(const ushort* __restrict__ Wb,
                                                 const float* __restrict__ ctxp,
                                                 ushort* __restrict__ Wc)
{
    const int oh = blockIdx.x, h = blockIdx.y, b = blockIdx.z;
    const int bh = b * 8 + h;
    __shared__ __align__(16) ushort ws[256 * 64];   // 32 KiB, Wout slice
    __shared__ __align__(16) ushort cs[64 * 64];    // 8 KiB, ctx[d][e]
    const int tid = threadIdx.x;
    const int w = tid >> 6, l = tid & 63;
    const int lq = l >> 4, lr = l & 15;

    // stage Wout rows oh*256..+255, cols h*64..+63 (8 chunks/row, swizzled)
    #pragma unroll
    for (int i = 0; i < 8; ++i) {
        int idx = i * 256 + tid;
        int row = idx >> 3;
        int ch = (idx & 7) ^ (row & 7);
        gload_lds16(Wb + (size_t)(oh * 256 + row) * 512 + h * 64 + ch * 8,
                    (char*)ws + idx * 16);
    }
    // sum ctx partials -> bf16 swizzled cs[d][e]
    {
        const float* cp = ctxp + (size_t)bh * 4 * 4096;
        const int d = tid >> 2, eb = (tid & 3) * 16;
        float vs[16];
        #pragma unroll
        for (int t4 = 0; t4 < 4; ++t4) {
            float4 a0 = *(const float4*)(cp + d * 64 + eb + t4 * 4);
            float4 a1 = *(const float4*)(cp + 4096 + d * 64 + eb + t4 * 4);
            float4 a2 = *(const float4*)(cp + 8192 + d * 64 + eb + t4 * 4);
            float4 a3 = *(const float4*)(cp + 12288 + d * 64 + eb + t4 * 4);
            vs[t4 * 4 + 0] = a0.x + a1.x + a2.x + a3.x;
            vs[t4 * 4 + 1] = a0.y + a1.y + a2.y + a3.y;
            vs[t4 * 4 + 2] = a0.z + a1.z + a2.z + a3.z;
            vs[t4 * 4 + 3] = a0.w + a1.w + a2.w + a3.w;
        }
        ushort8_t o0, o1;
        #pragma unroll
        for (int t = 0; t < 8; ++t) { o0[t] = f2bf(vs[t]); o1[t] = f2bf(vs[8 + t]); }
        const int c0 = (eb >> 3) ^ (d & 7);
        const int c1 = ((eb >> 3) + 1) ^ (d & 7);
        *(ushort8_t*)((char*)cs + (d * 8 + c0) * 16) = o0;
        *(ushort8_t*)((char*)cs + (d * 8 + c1) * 16) = o1;
    }
    __syncthreads();

    f32x4 acc[4][4];
    #pragma unroll
    for (int i = 0; i < 4; ++i)
        #pragma unroll
        for (int j = 0; j < 4; ++j)
            #pragma unroll
            for (int r = 0; r < 4; ++r) acc[i][j][r] = 0.f;

    #pragma unroll
    for (int kk = 0; kk < 2; ++kk) {
        bf16x8 af[4], bfr[4];
        #pragma unroll
        for (int mf = 0; mf < 4; ++mf) {
            int ra = w * 64 + mf * 16 + lr;
            int ch = (kk * 4 + lq) ^ (ra & 7);
            af[mf] = *(const bf16x8*)((const char*)ws + (ra * 8 + ch) * 16);
        }
        #pragma unroll
        for (int nf = 0; nf < 4; ++nf) {
            int rd = nf * 16 + lr;
            int ch = (kk * 4 + lq) ^ (rd & 7);
            bfr[nf] = *(const bf16x8*)((const char*)cs + (rd * 8 + ch) * 16);
        }
        #pragma unroll
        for (int mf = 0; mf < 4; ++mf)
            #pragma unroll
            for (int nf = 0; nf < 4; ++nf)
                acc[mf][nf] = __builtin_amdgcn_mfma_f32_16x16x32_bf16(
                    af[mf], bfr[nf], acc[mf][nf], 0, 0, 0);
    }

    ushort* wp = Wc + (size_t)b * 262144 + h * 64;
    #pragma unroll
    for (int mf = 0; mf < 4; ++mf)
        #pragma unroll
        for (int r = 0; r < 4; ++r) {
            const int o = oh * 256 + w * 64 + mf * 16 + lq * 4 + r;
            #pragma unroll
            for (int nf = 0; nf < 4; ++nf)
                wp[(size_t)o * 512 + nf * 16 + lr] = f2bf(acc[mf][nf][r]);
        }
}

// ---------------------------------------------------------------------------
// GEMM2 fused: out[b][o][n] = rmsnorm(Wc[b]@qT2[b] + bias) * g2, full column
// per block. 512 threads = 8 waves; wave w owns rows [w*64,w*64+64), n-tile 128.
// ---------------------------------------------------------------------------
__global__ __launch_bounds__(512, 2)
void gemm2_k(const ushort* __restrict__ Wc,     // [b][512][512] bf16
             const ushort* __restrict__ Bt,     // qT2 [b][n][512] bf16
             const float* __restrict__ bias,
             const float* __restrict__ g2,
             float* __restrict__ outp)
{
    __shared__ __align__(16) ushort As[512 * 64];   // 64 KiB
    __shared__ __align__(16) ushort Bs[128 * 64];   // 16 KiB
    const int b  = blockIdx.y;
    const int n0 = blockIdx.x * 128;
    const int tid = threadIdx.x;
    const int w = tid >> 6, l = tid & 63;
    const int lq = l >> 4, lr = l & 15;
    const ushort* A  = Wc + (size_t)b * 262144;
    const ushort* Bb = Bt + (size_t)b * N_ * 512;

    f32x4 acc[4][8];
    #pragma unroll
    for (int i = 0; i < 4; ++i)
        #pragma unroll
        for (int j = 0; j < 8; ++j)
            #pragma unroll
            for (int r = 0; r < 4; ++r) acc[i][j][r] = 0.f;

    for (int k0 = 0; k0 < 512; k0 += 64) {
        #pragma unroll
        for (int i = 0; i < 8; ++i) {
            int base = i * 512 + w * 64;           // wave-uniform chunk base
            int idx = base + l;
            int r = idx >> 3, ch = (idx & 7) ^ (r & 7);
            gload_lds16((const char*)A + (size_t)r * 1024 + k0 * 2 + ch * 16,
                        (char*)As + (size_t)base * 16);
        }
        #pragma unroll
        for (int i = 0; i < 2; ++i) {
            int base = i * 512 + w * 64;
            int idx = base + l;
            int r = idx >> 3, ch = (idx & 7) ^ (r & 7);
            gload_lds16((const char*)Bb + (size_t)(n0 + r) * 1024 + k0 * 2 + ch * 16,
                        (char*)Bs + (size_t)base * 16);
        }
        __syncthreads();
        #pragma unroll
        for (int kk = 0; kk < 2; ++kk) {
            bf16x8 af[4], bfv[8];
            #pragma unroll
            for (int mf = 0; mf < 4; ++mf) {
                int ra = w * 64 + mf * 16 + lr;
                int ch = (kk * 4 + lq) ^ (ra & 7);
                af[mf] = *(const bf16x8*)((const char*)As + ra * 128 + ch * 16);
            }
            #pragma unroll
            for (int nf = 0; nf < 8; ++nf) {
                int rb = nf * 16 + lr;
                int ch = (kk * 4 + lq) ^ (rb & 7);
                bfv[nf] = *(const bf16x8*)((const char*)Bs + rb * 128 + ch * 16);
            }
            #pragma unroll
            for (int mf = 0; mf < 4; ++mf)
                #pragma unroll
                for (int nf = 0; nf < 8; ++nf)
                    acc[mf][nf] = __builtin_amdgcn_mfma_f32_16x16x32_bf16(
                        af[mf], bfv[nf], acc[mf][nf], 0, 0, 0);
        }
        __syncthreads();
    }

    // epilogue: add bias, accumulate column sumsq, rms-norm, write final f32
    float4 bv[4], g2v[4];
    #pragma unroll
    for (int mf = 0; mf < 4; ++mf) {
        bv[mf]  = *reinterpret_cast<const float4*>(bias + w * 64 + mf * 16 + lq * 4);
        g2v[mf] = *reinterpret_cast<const float4*>(g2   + w * 64 + mf * 16 + lq * 4);
    }
    float csq[8] = {};
    #pragma unroll
    for (int mf = 0; mf < 4; ++mf)
        #pragma unroll
        for (int nf = 0; nf < 8; ++nf)
            #pragma unroll
            for (int r = 0; r < 4; ++r) {
                float wv = acc[mf][nf][r] + ((const float*)&bv[mf])[r];
                acc[mf][nf][r] = wv;
                csq[nf] += wv * wv;
            }
    #pragma unroll
    for (int nf = 0; nf < 8; ++nf) {
        csq[nf] += __shfl_xor(csq[nf], 16);
        csq[nf] += __shfl_xor(csq[nf], 32);
    }
    float* red  = (float*)As;       // 8 x 128 floats
    float* rs2s = red + 1024;       // 128 floats
    if (lq == 0) {
        #pragma unroll
        for (int nf = 0; nf < 8; ++nf)
            red[w * 128 + nf * 16 + lr] = csq[nf];
    }
    __syncthreads();
    if (tid < 128) {
        float s = 0.f;
        #pragma unroll
        for (int j = 0; j < 8; ++j) s += red[j * 128 + tid];
        rs2s[tid] = 22.627416998f / fmaxf(sqrtf(s), 1e-12f);
    }
    __syncthreads();
    #pragma unroll
    for (int nf = 0; nf < 8; ++nf) {
        const float rsv = rs2s[nf * 16 + lr];
        const int n = n0 + nf * 16 + lr;
        #pragma unroll
        for (int mf = 0; mf < 4; ++mf) {
            const int o = w * 64 + mf * 16 + lq * 4;
            float* p = outp + ((size_t)b * 512 + o) * N_ + n;
            #pragma unroll
            for (int r = 0; r < 4; ++r)
                p[(size_t)r * N_] = acc[mf][nf][r] * rsv * ((const float*)&g2v[mf])[r];
        }
    }
}

// ---------------------------------------------------------------------------
extern "C" void kernel_launch(void* const* d_in, const int* in_sizes, int n_in,
                              void* d_out, int out_size, void* d_ws, size_t ws_size,
                              hipStream_t stream)
{
    const float* x    = (const float*)d_in[0];
    const float* g1   = (const float*)d_in[1];
    const float* Wqkv = (const float*)d_in[2];
    const float* Wout = (const float*)d_in[3];
    const float* bout = (const float*)d_in[4];
    const float* g2   = (const float*)d_in[5];
    float* out = (float*)d_out;

    // ws layout (<= 258.25 MiB):
    //   [0,64Mi)     qT2 bf16 [b][n][512]  (csq1 f32 2Mi aliased pre-GEMM1)
    //   [64,128Mi)   kbuf bf16
    //   [128,192Mi)  vbuf bf16
    //   [192,256Mi)  Xt bf16              -> after GEMM1: ctxp f32 (8Mi) @192,
    //                                       rowm/rowr @200Mi, Wcb bf16 (8Mi) @201Mi
    //   [256Mi..)    Wqkvb(1.5Mi) Woutb(0.5Mi) rs1(256Ki)
    char* wsb = (char*)d_ws;
    ushort* qbuf  = (ushort*)wsb;
    float*  csq1  = (float*)wsb;     // alias (dead once rs1 computed)
    ushort* kbuf  = (ushort*)(wsb + ((size_t)64 << 20));
    ushort* vbuf  = (ushort*)(wsb + ((size_t)128 << 20));
    ushort* Xt    = (ushort*)(wsb + ((size_t)192 << 20));
    float*  ctxp  = (float*)Xt;
    float*  rowm  = (float*)(wsb + ((size_t)200 << 20));
    float*  rowr  = rowm + 8192;
    ushort* Wcb   = (ushort*)(wsb + ((size_t)201 << 20));
    char*   tail  = wsb + ((size_t)256 << 20);
    ushort* Wqkvb = (ushort*)tail;
    ushort* Woutb = (ushort*)(tail + (size_t)1536 * 512 * 2);
    float*  rs1   = (float*)(tail + (size_t)1536 * 512 * 2 + (size_t)512 * 512 * 2);

    // 1. weight prep (bf16; g1 folded into Wqkv)
    wprep_k<<<768, 256, 0, stream>>>(Wqkv, g1, Wqkvb, 1536 * 512 / 4);
    wprep_k<<<256, 256, 0, stream>>>(Wout, nullptr, Woutb, 512 * 512 / 4);
    // 2. Xt[b][n][c] = bf16(x^T) + column sumsq partials
    transpose_k<<<dim3(64, 8, 16), 256, 0, stream>>>(x, Xt, csq1);
    // 3. rs1 = sqrt(512)/||x_col||
    rs1_reduce_k<<<256, 256, 0, stream>>>(csq1, rs1);
    // 4. QKV GEMM: qT2 (softmaxed, [b][n][hd]), k, v (bf16)
    mfma_gemm<<<dim3(16, 6, B_), 512, 0, stream>>>(Wqkvb, Xt, rs1,
                                                   qbuf, kbuf, vbuf);
    // 5. k row stats (max, 1/sum-exp)
    rowstat_k<<<2048, 256, 0, stream>>>(kbuf, rowm, rowr);
    // 6. context partials (MFMA, softmax on the fly) -> ctxp[d][e]
    ctx_k<<<dim3(B_ * 8, 4), 256, 0, stream>>>(kbuf, vbuf, rowm, rowr, ctxp);
    // 7. Wc[b] = Wout @ ctx^T (per b,h), ctx partials summed in-kernel
    wcbuild_k<<<dim3(2, 8, B_), 256, 0, stream>>>(Woutb, ctxp, Wcb);
    // 8. output GEMM (per-b weights Wc) + bias + rms-norm -> d_out f32 (final)
    gemm2_k<<<dim3(32, B_), 512, 0, stream>>>(Wcb, qbuf, bout, g2, out);
}